// Round 8
// baseline (285.668 us; speedup 1.0000x reference)
//
#include <hip/hip_runtime.h>
#include <hip/hip_bf16.h>
#include <stdint.h>

// ---------------------------------------------------------------------------
// SplitCausalSelfAttention on MI355X (gfx950), bf16 MFMA implementation.
// B=4, T=2048, C=1024, H=16, D=64.
// R8: ALL epilogues rewritten as LDS-transpose + coalesced stores.  The old
//     C^T epilogues stored 8B/lane at 2-4KB lane stride = 64 cache lines per
//     store instr (~6M L2 transactions in qkv alone, ~13x payload inflation).
//     Now: stage C-frags to LDS (padded stride, <=2-way conflicts), barrier,
//     read back row-major, store 256B-contiguous runs (8-16 lines/instr).
//     Applied to Q/K/V (qkv), proj, and attn-Y.  Everything else = R7.
// ---------------------------------------------------------------------------

typedef unsigned short u16;
typedef __attribute__((ext_vector_type(8))) __bf16 bf16x8;  // 4 VGPRs (A/B frag, K=32)
typedef __attribute__((ext_vector_type(4))) float  f32x4;   // C/D frag
typedef __attribute__((ext_vector_type(4))) unsigned short u16x4;
typedef __attribute__((ext_vector_type(8))) unsigned short u16x8;
typedef __attribute__((ext_vector_type(4))) short s16x4;    // 2 VGPRs (A/B frag, K=16)

#define B_  4
#define T_  2048
#define C_  1024
#define H_  16
#define D_  64
#define BT_ (B_ * T_)

// scale = 1/sqrt(D) folded with log2(e) so softmax uses exp2
#define Q_SCALE 0.1803368801111204f

__device__ __forceinline__ u16 f32_to_bf16(float f) {
    unsigned int u = __float_as_uint(f);
    unsigned int r = (u + 0x7FFFu + ((u >> 16) & 1u)) >> 16;
    return (u16)r;
}

__device__ __forceinline__ unsigned int pk_bf16(float a, float b) {
    float2 f2; f2.x = a; f2.y = b;
    __hip_bfloat162 h = __float22bfloat162_rn(f2);
    return *(unsigned int*)&h;
}

__device__ __forceinline__ void async16(const void* g, void* lds) {
    __builtin_amdgcn_global_load_lds(
        (const __attribute__((address_space(1))) void*)g,
        (__attribute__((address_space(3))) void*)lds, 16, 0, 0);
}

// ---------------------------------------------------------------------------
// casts fp32 -> bf16
// ---------------------------------------------------------------------------
__global__ void cast_bf16_kernel(const float* __restrict__ in, u16* __restrict__ out, int n4) {
    int i = blockIdx.x * 256 + threadIdx.x;
    if (i >= n4) return;
    float4 v = ((const float4*)in)[i];
    u16x4 o;
    o[0] = f32_to_bf16(v.x); o[1] = f32_to_bf16(v.y);
    o[2] = f32_to_bf16(v.z); o[3] = f32_to_bf16(v.w);
    ((u16x4*)out)[i] = o;
}

__global__ void cast_w4_kernel(const float* __restrict__ w0, const float* __restrict__ w1,
                               const float* __restrict__ w2, const float* __restrict__ w3,
                               u16* __restrict__ o0, u16* __restrict__ o1,
                               u16* __restrict__ o2, u16* __restrict__ o3) {
    int which = blockIdx.y;
    const float* in = (which == 0) ? w0 : (which == 1) ? w1 : (which == 2) ? w2 : w3;
    u16* out = (which == 0) ? o0 : (which == 1) ? o1 : (which == 2) ? o2 : o3;
    int i = blockIdx.x * 256 + threadIdx.x;
    float4 v = ((const float4*)in)[i];
    u16x4 o;
    o[0] = f32_to_bf16(v.x); o[1] = f32_to_bf16(v.y);
    o[2] = f32_to_bf16(v.z); o[3] = f32_to_bf16(v.w);
    ((u16x4*)out)[i] = o;
}

// ---------------------------------------------------------------------------
// GEMM core, double-buffered: C[128x128] = A[128xK] * B[128xK]^T (NT).
// BK=32, global_load_lds width 16, 4 waves each 64x64 (4x4 MFMA).
// As: elems [0, 8192) of SM; Bs: elems [8192, 16384).
// ---------------------------------------------------------------------------
__device__ __forceinline__ void gemm_core_128_db(
    const u16* __restrict__ A, const u16* __restrict__ B,
    u16* As, u16* Bs, int m0, int n0, f32x4 (&acc)[4][4])
{
    const int K = C_;
    const int KT = K / 32;
    int tid  = threadIdx.x;
    int lane = tid & 63, w = tid >> 6;
    int quad = lane >> 4, l15 = lane & 15;
    int wm = w >> 1, wn = w & 1;

    int c0 = tid, c1 = tid + 256;
    int row0 = c0 >> 2, row1 = c1 >> 2;
    int gc0 = (((c0 & 3) - (row0 >> 1)) & 3) * 8;
    int gc1 = (((c1 & 3) - (row1 >> 1)) & 3) * 8;
    int ldsb0 = (w * 64) * 16;
    int ldsb1 = (256 + w * 64) * 16;

    const u16* ApA = A + (size_t)(m0 + row0) * K + gc0;
    const u16* ApB = A + (size_t)(m0 + row1) * K + gc1;
    const u16* BpA = B + (size_t)(n0 + row0) * K + gc0;
    const u16* BpB = B + (size_t)(n0 + row1) * K + gc1;

    char* As0 = (char*)As; char* As1 = (char*)As + 8192;
    char* Bs0 = (char*)Bs; char* Bs1 = (char*)Bs + 8192;

    int aoff[4], boff[4];
#pragma unroll
    for (int i = 0; i < 4; ++i) {
        int rA = wm * 64 + i * 16 + l15;
        aoff[i] = (rA * 32 + (((rA >> 1) + quad) & 3) * 8) * 2;
        int rB = wn * 64 + i * 16 + l15;
        boff[i] = (rB * 32 + (((rB >> 1) + quad) & 3) * 8) * 2;
    }

    // prologue: stage kt=0 into half 0
    async16(ApA, As0 + ldsb0); async16(ApB, As0 + ldsb1);
    async16(BpA, Bs0 + ldsb0); async16(BpB, Bs0 + ldsb1);
    ApA += 32; ApB += 32; BpA += 32; BpB += 32;

    auto body = [&](int kt, const char* Ac, const char* Bc, char* Apf, char* Bpf) {
        __syncthreads();   // drains vmcnt(0): tile kt resident; prev reads done
        if (kt + 1 < KT) {
            async16(ApA, Apf + ldsb0); async16(ApB, Apf + ldsb1);
            async16(BpA, Bpf + ldsb0); async16(BpB, Bpf + ldsb1);
        }
        ApA += 32; ApB += 32; BpA += 32; BpB += 32;

        bf16x8 a[4], b[4];
#pragma unroll
        for (int i = 0; i < 4; ++i) {
            a[i] = *(const bf16x8*)(Ac + aoff[i]);
            b[i] = *(const bf16x8*)(Bc + boff[i]);
        }
#pragma unroll
        for (int i = 0; i < 4; ++i)
#pragma unroll
            for (int j = 0; j < 4; ++j)
                acc[i][j] = __builtin_amdgcn_mfma_f32_16x16x32_bf16(a[i], b[j], acc[i][j], 0, 0, 0);
    };

    for (int kt = 0; kt < KT; kt += 2) {
        body(kt,     As0, Bs0, As1, Bs1);
        body(kt + 1, As1, Bs1, As0, Bs0);
    }
}

// ---------------------------------------------------------------------------
// Fused QKV projection, XCD-pinned 1-D grid (1536 blocks).
// which 0/1 (Q/K): C^T orientation; which 2 (V): C orientation.
// Epilogue: LDS transpose (stride 132, <=2-way banks) -> coalesced stores:
// each 8B store covers 2 contiguous 256B rows (8 lines) instead of 64 lines.
// ---------------------------------------------------------------------------
__global__ __launch_bounds__(256, 4) void qkv_gemm(
    const u16* __restrict__ Xb,
    const u16* __restrict__ Wqb, const u16* __restrict__ Wkb, const u16* __restrict__ Wvb,
    u16* __restrict__ Qb, u16* __restrict__ Kb, u16* __restrict__ Vtb)
{
    __shared__ u16 SM[17408];        // 34816 B: K-loop buffers, then transpose pad
    u16* As = SM;                    // [0, 8192)
    u16* Bs = SM + 8192;             // [8192, 16384)

    int id = blockIdx.x;
    int xcd = id & 7;
    int local = id >> 3;          // 0..191
    int yloc = local & 7;
    int zx = local >> 3;          // 0..23
    int bx = zx & 7;              // channel tile
    int which = zx >> 3;          // 0..2
    int by = xcd * 8 + yloc;      // t tile 0..63

    const u16* W = (which == 0) ? Wqb : ((which == 1) ? Wkb : Wvb);

    f32x4 acc[4][4];
    const f32x4 z4 = {0.f, 0.f, 0.f, 0.f};
#pragma unroll
    for (int i = 0; i < 4; ++i)
#pragma unroll
        for (int j = 0; j < 4; ++j) acc[i][j] = z4;

    int tid = threadIdx.x;
    int lane = tid & 63, w = tid >> 6;
    int quad = lane >> 4, l15 = lane & 15;
    int wm = w >> 1, wn = w & 1;

    if (which <= 1) {
        int m0 = bx * 128, n0 = by * 128;   // m=channels, n=t
        gemm_core_128_db(W, Xb, As, Bs, m0, n0, acc);
        float s = (which == 0) ? Q_SCALE : 1.0f;
        u16* Out = (which == 0) ? Qb : Kb;

        __syncthreads();   // K-loop LDS reads done; repurpose SM
        // stage: SM[t*132 + ch] bf16
#pragma unroll
        for (int i = 0; i < 4; ++i) {
            int chl = wm * 64 + i * 16 + quad * 4;
#pragma unroll
            for (int j = 0; j < 4; ++j) {
                int tl = wn * 64 + j * 16 + l15;
                u16x4 v;
#pragma unroll
                for (int r = 0; r < 4; ++r) v[r] = f32_to_bf16(acc[i][j][r] * s);
                *(u16x4*)&SM[tl * 132 + chl] = v;
            }
        }
        __syncthreads();
        // store: 2 t-rows per instr, 256B contiguous per row
#pragma unroll
        for (int st = 0; st < 16; ++st) {
            int tl = w * 32 + st * 2 + (lane >> 5);
            int ch4 = (lane & 31) * 4;
            u16x4 v = *(u16x4*)&SM[tl * 132 + ch4];
            *(u16x4*)&Out[(size_t)(n0 + tl) * C_ + m0 + ch4] = v;
        }
    } else {
        int m0 = by * 128, n0 = bx * 128;   // m=t, n=channels
        gemm_core_128_db(Xb, W, As, Bs, m0, n0, acc);

        __syncthreads();
        // stage: SM[ch*132 + t] bf16  (lane holds 4 consecutive t at fixed ch)
#pragma unroll
        for (int i = 0; i < 4; ++i) {
            int tl0 = wm * 64 + i * 16 + quad * 4;
#pragma unroll
            for (int j = 0; j < 4; ++j) {
                int chl = wn * 64 + j * 16 + l15;
                u16x4 v;
#pragma unroll
                for (int r = 0; r < 4; ++r) v[r] = f32_to_bf16(acc[i][j][r]);
                *(u16x4*)&SM[chl * 132 + tl0] = v;
            }
        }
        __syncthreads();
        // store into Vt[B,H,D,T]: 2 d-rows per instr, contiguous along T
        int bb = m0 >> 11;
        int tbase = m0 & (T_ - 1);
#pragma unroll
        for (int st = 0; st < 16; ++st) {
            int chl = w * 32 + st * 2 + (lane >> 5);
            int t4 = (lane & 31) * 4;
            u16x4 v = *(u16x4*)&SM[chl * 132 + t4];
            int col = n0 + chl;
            int h = col >> 6, d = col & 63;
            *(u16x4*)&Vtb[(((bb * H_ + h) * D_ + d) * T_) + tbase + t4] = v;
        }
    }
}

// ---------------------------------------------------------------------------
// Flash attention (causal), S^T/O^T, max-free softmax, register-resident P.
// Block = 128 Q rows (4 waves x 32 t-cols), one (b,h).  K-tile = 64 rows.
// Balanced 1-D grid decode (complement schedule) + XCD pinning.
// R8: Y epilogue via LDS transpose (wave-private, stride 72) -> 16B/lane
// stores over contiguous 128B rows.
// ---------------------------------------------------------------------------
__global__ __launch_bounds__(256) void attn_kernel(
    const u16* __restrict__ Qb, const u16* __restrict__ Kb,
    const u16* __restrict__ Vtb, u16* __restrict__ Yb)
{
    __shared__ u16 SMA[16384];       // Ks0|Ks1|Vs0|Vs1 (4x8KB), reused by epilogue
    u16* Ks0 = SMA;
    u16* Ks1 = SMA + 4096;
    u16* Vs0 = SMA + 8192;
    u16* Vs1 = SMA + 12288;

    int id = blockIdx.x;
    int kk = id >> 8;                // 0..3
    int cc = id & 255;
    int jj = cc >> 6;                // 0..3
    int bh = cc & 63;
    int qt = (kk == 0) ? jj : (kk == 1) ? (15 - jj) : (kk == 2) ? (jj + 4) : (11 - jj);

    int tid = threadIdx.x, lane = tid & 63, w = tid >> 6;
    int quad = lane >> 4, l15 = lane & 15;
    int qbase = qt * 128;
    int b = bh >> 4, h = bh & 15;

    // Q B-frags from [BT,C]: 2 col-groups x 2 k-halves, 16B contiguous/lane
    bf16x8 qf[2][2];
    {
        const u16* q0 = Qb + ((size_t)(b * T_ + qbase + w * 32 + l15)) * C_ + h * 64;
        qf[0][0] = *(const bf16x8*)(q0 + quad * 8);
        qf[0][1] = *(const bf16x8*)(q0 + 32 + quad * 8);
        const u16* q1 = q0 + 16 * C_;
        qf[1][0] = *(const bf16x8*)(q1 + quad * 8);
        qf[1][1] = *(const bf16x8*)(q1 + 32 + quad * 8);
    }

    // loop-invariant LDS byte offsets (K: 8 x b128, V: 16 x b64)
    int koff0[4], koff1[4], voff[4][4];
#pragma unroll
    for (int sblk = 0; sblk < 4; ++sblk) {
        int sr = sblk * 16 + l15;
        koff0[sblk] = (sr * 64 + ((quad + sr) & 7) * 8) * 2;
        koff1[sblk] = (sr * 64 + ((4 + quad + sr) & 7) * 8) * 2;
    }
#pragma unroll
    for (int n = 0; n < 4; ++n)
#pragma unroll
        for (int sblk = 0; sblk < 4; ++sblk) {
            int dr = n * 16 + l15;
            voff[n][sblk] = (dr * 64 + ((sblk * 2 + (quad >> 1) + dr) & 7) * 8 + (quad & 1) * 4) * 2;
        }

    float l_part[2] = {0.f, 0.f};
    f32x4 o_acc[2][4];               // O^T: col t (l15), rows d=n*16+quad*4+r
    const f32x4 z4 = {0.f, 0.f, 0.f, 0.f};
#pragma unroll
    for (int c = 0; c < 2; ++c)
#pragma unroll
        for (int n = 0; n < 4; ++n) o_acc[c][n] = z4;

    // staging chunk assignment (512 chunks of 16B per 8KB tile, 2 passes)
    int cA = tid, cB = tid + 256;
    int sA = cA >> 3, sB = cB >> 3;
    int offA = (((cA & 7) - sA) & 7) * 8;
    int offB = (((cB & 7) - sB) & 7) * 8;
    const u16* Kbase = Kb + (size_t)(b * T_) * C_ + h * 64;
    const u16* Vbase = Vtb + (size_t)bh * D_ * T_;
    int ldsb0 = (w * 64) * 16, ldsb1 = (256 + w * 64) * 16;

    const int nst = 2 * qt + 2;      // always even

    const u16* kgpA = Kbase + (size_t)sA * C_ + offA;
    const u16* kgpB = Kbase + (size_t)sB * C_ + offB;
    const u16* vgpA = Vbase + sA * T_ + offA;
    const u16* vgpB = Vbase + sB * T_ + offB;

    // prologue: stage tile 0 into buffer 0
    async16(kgpA, (char*)Ks0 + ldsb0);
    async16(kgpB, (char*)Ks0 + ldsb1);
    async16(vgpA, (char*)Vs0 + ldsb0);
    async16(vgpB, (char*)Vs0 + ldsb1);
    kgpA += 64 * C_; kgpB += 64 * C_; vgpA += 64; vgpB += 64;

    auto tile_body = [&](int st, const u16* K_, const u16* V_, char* Kpf, char* Vpf) {
        __syncthreads();   // drains vmcnt(0): tile st resident; prev reads done
        if (st + 1 < nst) {
            async16(kgpA, Kpf + ldsb0);
            async16(kgpB, Kpf + ldsb1);
            async16(vgpA, Vpf + ldsb0);
            async16(vgpB, Vpf + ldsb1);
        }
        kgpA += 64 * C_; kgpB += 64 * C_; vgpA += 64; vgpB += 64;

        // S^T = K Q^T : per wave 64(s) x 32(t), K frags shared across c
        f32x4 sv[2][4];
#pragma unroll
        for (int sblk = 0; sblk < 4; ++sblk) {
            bf16x8 k0 = *(const bf16x8*)((const char*)K_ + koff0[sblk]);
            bf16x8 k1 = *(const bf16x8*)((const char*)K_ + koff1[sblk]);
#pragma unroll
            for (int c = 0; c < 2; ++c) {
                f32x4 t0 = __builtin_amdgcn_mfma_f32_16x16x32_bf16(k0, qf[c][0], z4, 0, 0, 0);
                sv[c][sblk] = __builtin_amdgcn_mfma_f32_16x16x32_bf16(k1, qf[c][1], t0, 0, 0, 0);
            }
        }

        if (st >= 2 * qt) {   // diagonal region: causal mask (s > t)
            int sb0 = st * 64 - qbase;
#pragma unroll
            for (int c = 0; c < 2; ++c) {
                int tl = w * 32 + c * 16 + l15;
#pragma unroll
                for (int sblk = 0; sblk < 4; ++sblk)
#pragma unroll
                    for (int r = 0; r < 4; ++r)
                        if (sb0 + sblk * 16 + quad * 4 + r > tl) sv[c][sblk][r] = -1e30f;
            }
        }

        // max-free softmax: raw v_exp_f32, lane-local sum, P packed to regs
        s16x4 pfrag[2][4];
#pragma unroll
        for (int c = 0; c < 2; ++c) {
            f32x4 s4 = z4;
#pragma unroll
            for (int sblk = 0; sblk < 4; ++sblk) {
#pragma unroll
                for (int r = 0; r < 4; ++r)
                    sv[c][sblk][r] = __builtin_amdgcn_exp2f(sv[c][sblk][r]);
                s4 += sv[c][sblk];
                uint2 pk;
                pk.x = pk_bf16(sv[c][sblk][0], sv[c][sblk][1]);
                pk.y = pk_bf16(sv[c][sblk][2], sv[c][sblk][3]);
                pfrag[c][sblk] = *(s16x4*)&pk;
            }
            l_part[c] += (s4[0] + s4[1]) + (s4[2] + s4[3]);
        }

        // O^T += V^T P via mfma 16x16x16: A = V^T (LDS b64), B = pfrag (regs)
#pragma unroll
        for (int n = 0; n < 4; ++n)
#pragma unroll
            for (int sblk = 0; sblk < 4; ++sblk) {
                s16x4 va = *(const s16x4*)((const char*)V_ + voff[n][sblk]);
#pragma unroll
                for (int c = 0; c < 2; ++c)
                    o_acc[c][n] = __builtin_amdgcn_mfma_f32_16x16x16bf16_1k(va, pfrag[c][sblk], o_acc[c][n], 0, 0, 0);
            }
    };

    for (int st = 0; st < nst; st += 2) {
        tile_body(st,     Ks0, Vs0, (char*)Ks1, (char*)Vs1);
        tile_body(st + 1, Ks1, Vs1, (char*)Ks0, (char*)Vs0);
    }

    // epilogue: LDS transpose (wave-private region, stride 72) -> coalesced
    __syncthreads();                 // all waves done reading K/V LDS
    u16* PW = SMA + w * 2304;        // 32 rows x 72 elems per wave
#pragma unroll
    for (int c = 0; c < 2; ++c) {
        float l = l_part[c];
        l += __shfl_xor(l, 16, 64);
        l += __shfl_xor(l, 32, 64);
        float inv = 1.0f / l;
#pragma unroll
        for (int n = 0; n < 4; ++n) {
            u16x4 v;
            uint2 pk;
            pk.x = pk_bf16(o_acc[c][n][0] * inv, o_acc[c][n][1] * inv);
            pk.y = pk_bf16(o_acc[c][n][2] * inv, o_acc[c][n][3] * inv);
            v = *(u16x4*)&pk;
            *(u16x4*)&PW[(c * 16 + l15) * 72 + n * 16 + quad * 4] = v;
        }
    }
    asm volatile("s_waitcnt lgkmcnt(0)" ::: "memory");   // wave-private: no barrier
#pragma unroll
    for (int st = 0; st < 4; ++st) {
        int tr = st * 8 + (lane >> 3);      // 0..31
        int d8 = (lane & 7) * 8;
        u16x8 v = *(u16x8*)&PW[tr * 72 + d8];
        *(u16x8*)&Yb[(size_t)(b * T_ + qbase + w * 32 + tr) * C_ + h * 64 + d8] = v;
    }
}

// ---------------------------------------------------------------------------
// Output projection, XCD-pinned 1-D grid (512 blocks), C^T orientation.
// Epilogue: fp32 LDS transpose in 2 ch-halves (stride 68) -> float4 stores
// over contiguous 256B rows (4 rows per instr).
// ---------------------------------------------------------------------------
__global__ __launch_bounds__(256, 4) void proj_gemm(
    const u16* __restrict__ Yb, const u16* __restrict__ Wob,
    const float* __restrict__ bo, float* __restrict__ out)
{
    __shared__ u16 SM[17408];        // 34816 B = 128*68 floats exactly
    u16* As = SM;
    u16* Bs = SM + 8192;

    int id = blockIdx.x;
    int xcd = id & 7;
    int local = id >> 3;          // 0..63
    int by = xcd * 8 + (local & 7);
    int bx = local >> 3;          // 0..7
    int m0 = bx * 128, n0 = by * 128;   // m=channels, n=t

    f32x4 acc[4][4];
    const f32x4 z4 = {0.f, 0.f, 0.f, 0.f};
#pragma unroll
    for (int i = 0; i < 4; ++i)
#pragma unroll
        for (int j = 0; j < 4; ++j) acc[i][j] = z4;

    gemm_core_128_db(Wob, Yb, As, Bs, m0, n0, acc);

    int lane = threadIdx.x & 63, w = threadIdx.x >> 6;
    int quad = lane >> 4, l15 = lane & 15;
    int wm = w >> 1, wn = w & 1;

    float* LF = (float*)SM;          // [t][68] fp32
    __syncthreads();                 // K-loop LDS reads done
#pragma unroll
    for (int hh = 0; hh < 2; ++hh) {
        if (wm == hh) {
#pragma unroll
            for (int i = 0; i < 4; ++i) {
                int chl = i * 16 + quad * 4;             // within this half
#pragma unroll
                for (int j = 0; j < 4; ++j) {
                    int tl = wn * 64 + j * 16 + l15;
                    *(f32x4*)&LF[tl * 68 + chl] = acc[i][j];
                }
            }
        }
        __syncthreads();
        f32x4 b4 = *(const f32x4*)&bo[m0 + hh * 64 + (lane & 15) * 4];
#pragma unroll
        for (int st = 0; st < 8; ++st) {
            int tl = w * 32 + st * 4 + (lane >> 4);      // 4 t-rows per store
            int ch4 = (lane & 15) * 4;
            f32x4 v = *(f32x4*)&LF[tl * 68 + ch4];
            v += b4;
            *(f32x4*)&out[(size_t)(n0 + tl) * C_ + m0 + hh * 64 + ch4] = v;
        }
        if (hh == 0) __syncthreads();
    }
}

// ---------------------------------------------------------------------------
// launch
// ---------------------------------------------------------------------------
extern "C" void kernel_launch(void* const* d_in, const int* in_sizes, int n_in,
                              void* d_out, int out_size, void* d_ws, size_t ws_size,
                              hipStream_t stream) {
    const float* X  = (const float*)d_in[0];
    const float* Wq = (const float*)d_in[1];
    const float* Wk = (const float*)d_in[2];
    const float* Wv = (const float*)d_in[3];
    const float* Wo = (const float*)d_in[4];
    const float* bo = (const float*)d_in[5];

    char* ws = (char*)d_ws;
    u16* Xb  = (u16*)(ws);                       // 16 MB  [BT, C] bf16
    u16* Wqb = (u16*)(ws + (16u << 20));         //  2 MB
    u16* Wkb = (u16*)(ws + (18u << 20));         //  2 MB
    u16* Wvb = (u16*)(ws + (20u << 20));         //  2 MB
    u16* Wob = (u16*)(ws + (22u << 20));         //  2 MB
    u16* Qb  = (u16*)(ws + (24u << 20));         // 16 MB  [BT, C] (pre-scaled)
    u16* Kb  = (u16*)(ws + (40u << 20));         // 16 MB  [BT, C]
    u16* Vtb = (u16*)(ws + (56u << 20));         // 16 MB  [B,H,D,T]
    u16* Yb  = (u16*)(ws + (72u << 20));         // 16 MB  [BT, C]

    cast_bf16_kernel<<<(BT_ * C_ / 4) / 256, 256, 0, stream>>>(X, Xb, BT_ * C_ / 4);
    cast_w4_kernel<<<dim3((C_ * C_ / 4) / 256, 4), 256, 0, stream>>>(
        Wq, Wk, Wv, Wo, Wqb, Wkb, Wvb, Wob);

    qkv_gemm<<<dim3(3 * 8 * 64), 256, 0, stream>>>(Xb, Wqb, Wkb, Wvb, Qb, Kb, Vtb);
    attn_kernel<<<dim3((T_ / 128) * B_ * H_), 256, 0, stream>>>(Qb, Kb, Vtb, Yb);
    proj_gemm<<<dim3(8 * 64), 256, 0, stream>>>(Yb, Wob, bo, (float*)d_out);
}

// Round 9
// 264.077 us; speedup vs baseline: 1.0818x; 1.0818x over previous
//
#include <hip/hip_runtime.h>
#include <hip/hip_bf16.h>
#include <stdint.h>

// ---------------------------------------------------------------------------
// SplitCausalSelfAttention on MI355X (gfx950), bf16 MFMA implementation.
// B=4, T=2048, C=1024, H=16, D=64.
// R9: QKV FUSED into one kernel: each block computes Q,K,V for one
//     (128 t x 128 ch) tile, staging the X tile ONCE per K-chunk plus the
//     three W tiles (32KB staged / 48 MFMA per wave per iter = 1.5x arith
//     intensity, 3x MFMA per barrier).  Q/K via mfma(Wfrag, Xfrag) -> C^T
//     (8B stores, R7 pattern), V via mfma(Xfrag, Wfrag) -> C (8B stores along
//     T).  R8's LDS-transpose epilogues reverted for qkv (falsified: store
//     scatter was never the limiter).  attn/proj unchanged from R8.
// ---------------------------------------------------------------------------

typedef unsigned short u16;
typedef __attribute__((ext_vector_type(8))) __bf16 bf16x8;  // 4 VGPRs (A/B frag, K=32)
typedef __attribute__((ext_vector_type(4))) float  f32x4;   // C/D frag
typedef __attribute__((ext_vector_type(4))) unsigned short u16x4;
typedef __attribute__((ext_vector_type(8))) unsigned short u16x8;
typedef __attribute__((ext_vector_type(4))) short s16x4;    // 2 VGPRs (A/B frag, K=16)

#define B_  4
#define T_  2048
#define C_  1024
#define H_  16
#define D_  64
#define BT_ (B_ * T_)

// scale = 1/sqrt(D) folded with log2(e) so softmax uses exp2
#define Q_SCALE 0.1803368801111204f

__device__ __forceinline__ u16 f32_to_bf16(float f) {
    unsigned int u = __float_as_uint(f);
    unsigned int r = (u + 0x7FFFu + ((u >> 16) & 1u)) >> 16;
    return (u16)r;
}

__device__ __forceinline__ unsigned int pk_bf16(float a, float b) {
    float2 f2; f2.x = a; f2.y = b;
    __hip_bfloat162 h = __float22bfloat162_rn(f2);
    return *(unsigned int*)&h;
}

__device__ __forceinline__ void async16(const void* g, void* lds) {
    __builtin_amdgcn_global_load_lds(
        (const __attribute__((address_space(1))) void*)g,
        (__attribute__((address_space(3))) void*)lds, 16, 0, 0);
}

// ---------------------------------------------------------------------------
// casts fp32 -> bf16
// ---------------------------------------------------------------------------
__global__ void cast_bf16_kernel(const float* __restrict__ in, u16* __restrict__ out, int n4) {
    int i = blockIdx.x * 256 + threadIdx.x;
    if (i >= n4) return;
    float4 v = ((const float4*)in)[i];
    u16x4 o;
    o[0] = f32_to_bf16(v.x); o[1] = f32_to_bf16(v.y);
    o[2] = f32_to_bf16(v.z); o[3] = f32_to_bf16(v.w);
    ((u16x4*)out)[i] = o;
}

__global__ void cast_w4_kernel(const float* __restrict__ w0, const float* __restrict__ w1,
                               const float* __restrict__ w2, const float* __restrict__ w3,
                               u16* __restrict__ o0, u16* __restrict__ o1,
                               u16* __restrict__ o2, u16* __restrict__ o3) {
    int which = blockIdx.y;
    const float* in = (which == 0) ? w0 : (which == 1) ? w1 : (which == 2) ? w2 : w3;
    u16* out = (which == 0) ? o0 : (which == 1) ? o1 : (which == 2) ? o2 : o3;
    int i = blockIdx.x * 256 + threadIdx.x;
    float4 v = ((const float4*)in)[i];
    u16x4 o;
    o[0] = f32_to_bf16(v.x); o[1] = f32_to_bf16(v.y);
    o[2] = f32_to_bf16(v.z); o[3] = f32_to_bf16(v.w);
    ((u16x4*)out)[i] = o;
}

// ---------------------------------------------------------------------------
// Fused QKV GEMM.  Grid 512 = 64 t-tiles (XCD-pinned) x 8 ch-tiles.
// Per block: 128t x 128ch of Q, K, V.  K-loop BK=32, double-buffered,
// staging X + Wq + Wk + Wv tiles (8 async16/thread/iter), 48 MFMA/wave/iter.
// ---------------------------------------------------------------------------
__global__ __launch_bounds__(256, 2) void qkv_gemm(
    const u16* __restrict__ Xb,
    const u16* __restrict__ Wqb, const u16* __restrict__ Wkb, const u16* __restrict__ Wvb,
    u16* __restrict__ Qb, u16* __restrict__ Kb, u16* __restrict__ Vtb)
{
    __shared__ u16 Xs[8192];         // 2 x 8KB halves
    __shared__ u16 Wqs[8192], Wks[8192], Wvs[8192];

    int id = blockIdx.x;
    int xcd = id & 7;
    int local = id >> 3;             // 0..63
    int tt = xcd * 8 + (local & 7);  // t tile 0..63 (XCD-pinned X slice)
    int ct = local >> 3;             // ch tile 0..7
    int m0 = tt * 128, n0 = ct * 128;

    int tid = threadIdx.x, lane = tid & 63, w = tid >> 6;
    int quad = lane >> 4, l15 = lane & 15;
    int wm = w >> 1, wn = w & 1;

    // staging chunk assignment (512 chunks of 16B per 128x32 tile, 2 passes)
    int c0 = tid, c1 = tid + 256;
    int row0 = c0 >> 2, row1 = c1 >> 2;
    int gc0 = (((c0 & 3) - (row0 >> 1)) & 3) * 8;
    int gc1 = (((c1 & 3) - (row1 >> 1)) & 3) * 8;
    int ldsb0 = (w * 64) * 16;
    int ldsb1 = (256 + w * 64) * 16;

    const u16* xp0 = Xb  + (size_t)(m0 + row0) * C_ + gc0;
    const u16* xp1 = Xb  + (size_t)(m0 + row1) * C_ + gc1;
    const u16* wq0 = Wqb + (size_t)(n0 + row0) * C_ + gc0;
    const u16* wq1 = Wqb + (size_t)(n0 + row1) * C_ + gc1;
    const u16* wk0 = Wkb + (size_t)(n0 + row0) * C_ + gc0;
    const u16* wk1 = Wkb + (size_t)(n0 + row1) * C_ + gc1;
    const u16* wv0 = Wvb + (size_t)(n0 + row0) * C_ + gc0;
    const u16* wv1 = Wvb + (size_t)(n0 + row1) * C_ + gc1;

    // loop-invariant swizzled frag byte offsets within a 128x32 tile
    int aoff[4], boff[4];
#pragma unroll
    for (int i = 0; i < 4; ++i) {
        int rA = wm * 64 + i * 16 + l15;
        aoff[i] = (rA * 32 + (((rA >> 1) + quad) & 3) * 8) * 2;
        int rB = wn * 64 + i * 16 + l15;
        boff[i] = (rB * 32 + (((rB >> 1) + quad) & 3) * 8) * 2;
    }

    f32x4 aq[4][4], ak[4][4], av[4][4];   // [Afrag][Bfrag]
    const f32x4 z4 = {0.f, 0.f, 0.f, 0.f};
#pragma unroll
    for (int i = 0; i < 4; ++i)
#pragma unroll
        for (int j = 0; j < 4; ++j) { aq[i][j] = z4; ak[i][j] = z4; av[i][j] = z4; }

    // prologue: stage kt=0 into half 0
    async16(xp0, (char*)Xs  + ldsb0); async16(xp1, (char*)Xs  + ldsb1);
    async16(wq0, (char*)Wqs + ldsb0); async16(wq1, (char*)Wqs + ldsb1);
    async16(wk0, (char*)Wks + ldsb0); async16(wk1, (char*)Wks + ldsb1);
    async16(wv0, (char*)Wvs + ldsb0); async16(wv1, (char*)Wvs + ldsb1);
    xp0 += 32; xp1 += 32; wq0 += 32; wq1 += 32;
    wk0 += 32; wk1 += 32; wv0 += 32; wv1 += 32;

    auto body = [&](int kt, int cur, int nxt) {
        __syncthreads();   // tile kt resident; previous frag reads done
        if (kt + 1 < 32) {
            async16(xp0, (char*)Xs  + nxt + ldsb0); async16(xp1, (char*)Xs  + nxt + ldsb1);
            async16(wq0, (char*)Wqs + nxt + ldsb0); async16(wq1, (char*)Wqs + nxt + ldsb1);
            async16(wk0, (char*)Wks + nxt + ldsb0); async16(wk1, (char*)Wks + nxt + ldsb1);
            async16(wv0, (char*)Wvs + nxt + ldsb0); async16(wv1, (char*)Wvs + nxt + ldsb1);
        }
        xp0 += 32; xp1 += 32; wq0 += 32; wq1 += 32;
        wk0 += 32; wk1 += 32; wv0 += 32; wv1 += 32;

        bf16x8 xa[4];
#pragma unroll
        for (int i = 0; i < 4; ++i)
            xa[i] = *(const bf16x8*)((const char*)Xs + cur + aoff[i]);

        bf16x8 bb[4];
#pragma unroll
        for (int j = 0; j < 4; ++j)
            bb[j] = *(const bf16x8*)((const char*)Wqs + cur + boff[j]);
#pragma unroll
        for (int j = 0; j < 4; ++j)
#pragma unroll
            for (int i = 0; i < 4; ++i)
                aq[j][i] = __builtin_amdgcn_mfma_f32_16x16x32_bf16(bb[j], xa[i], aq[j][i], 0, 0, 0);

#pragma unroll
        for (int j = 0; j < 4; ++j)
            bb[j] = *(const bf16x8*)((const char*)Wks + cur + boff[j]);
#pragma unroll
        for (int j = 0; j < 4; ++j)
#pragma unroll
            for (int i = 0; i < 4; ++i)
                ak[j][i] = __builtin_amdgcn_mfma_f32_16x16x32_bf16(bb[j], xa[i], ak[j][i], 0, 0, 0);

#pragma unroll
        for (int j = 0; j < 4; ++j)
            bb[j] = *(const bf16x8*)((const char*)Wvs + cur + boff[j]);
#pragma unroll
        for (int i = 0; i < 4; ++i)
#pragma unroll
            for (int j = 0; j < 4; ++j)
                av[i][j] = __builtin_amdgcn_mfma_f32_16x16x32_bf16(xa[i], bb[j], av[i][j], 0, 0, 0);
    };

    for (int kt = 0; kt < 32; kt += 2) {
        body(kt,     0,    8192);
        body(kt + 1, 8192, 0);
    }

    // Q/K epilogue (C^T): lane holds 4 consecutive channels at fixed t
#pragma unroll
    for (int j = 0; j < 4; ++j) {
        int ch0 = n0 + wn * 64 + j * 16 + quad * 4;
#pragma unroll
        for (int i = 0; i < 4; ++i) {
            int t = m0 + wm * 64 + i * 16 + l15;
            u16x4 vq, vk;
#pragma unroll
            for (int r = 0; r < 4; ++r) {
                vq[r] = f32_to_bf16(aq[j][i][r] * Q_SCALE);
                vk[r] = f32_to_bf16(ak[j][i][r]);
            }
            *(u16x4*)&Qb[(size_t)t * C_ + ch0] = vq;
            *(u16x4*)&Kb[(size_t)t * C_ + ch0] = vk;
        }
    }
    // V epilogue (C): lane holds 4 consecutive t at fixed channel -> [B,H,D,T]
#pragma unroll
    for (int i = 0; i < 4; ++i) {
        int t0 = m0 + wm * 64 + i * 16 + quad * 4;
        int bb_ = t0 >> 11, tloc = t0 & (T_ - 1);
#pragma unroll
        for (int j = 0; j < 4; ++j) {
            int col = n0 + wn * 64 + j * 16 + l15;
            int h = col >> 6, d = col & 63;
            u16x4 v;
#pragma unroll
            for (int r = 0; r < 4; ++r) v[r] = f32_to_bf16(av[i][j][r]);
            *(u16x4*)&Vtb[(((bb_ * H_ + h) * D_ + d) * T_) + tloc] = v;
        }
    }
}

// ---------------------------------------------------------------------------
// GEMM core, double-buffered (used by proj): C[128x128] = A[128xK]*B[128xK]^T.
// ---------------------------------------------------------------------------
__device__ __forceinline__ void gemm_core_128_db(
    const u16* __restrict__ A, const u16* __restrict__ B,
    u16* As, u16* Bs, int m0, int n0, f32x4 (&acc)[4][4])
{
    const int K = C_;
    const int KT = K / 32;
    int tid  = threadIdx.x;
    int lane = tid & 63, w = tid >> 6;
    int quad = lane >> 4, l15 = lane & 15;
    int wm = w >> 1, wn = w & 1;

    int c0 = tid, c1 = tid + 256;
    int row0 = c0 >> 2, row1 = c1 >> 2;
    int gc0 = (((c0 & 3) - (row0 >> 1)) & 3) * 8;
    int gc1 = (((c1 & 3) - (row1 >> 1)) & 3) * 8;
    int ldsb0 = (w * 64) * 16;
    int ldsb1 = (256 + w * 64) * 16;

    const u16* ApA = A + (size_t)(m0 + row0) * K + gc0;
    const u16* ApB = A + (size_t)(m0 + row1) * K + gc1;
    const u16* BpA = B + (size_t)(n0 + row0) * K + gc0;
    const u16* BpB = B + (size_t)(n0 + row1) * K + gc1;

    char* As0 = (char*)As; char* As1 = (char*)As + 8192;
    char* Bs0 = (char*)Bs; char* Bs1 = (char*)Bs + 8192;

    int aoff[4], boff[4];
#pragma unroll
    for (int i = 0; i < 4; ++i) {
        int rA = wm * 64 + i * 16 + l15;
        aoff[i] = (rA * 32 + (((rA >> 1) + quad) & 3) * 8) * 2;
        int rB = wn * 64 + i * 16 + l15;
        boff[i] = (rB * 32 + (((rB >> 1) + quad) & 3) * 8) * 2;
    }

    async16(ApA, As0 + ldsb0); async16(ApB, As0 + ldsb1);
    async16(BpA, Bs0 + ldsb0); async16(BpB, Bs0 + ldsb1);
    ApA += 32; ApB += 32; BpA += 32; BpB += 32;

    auto body = [&](int kt, const char* Ac, const char* Bc, char* Apf, char* Bpf) {
        __syncthreads();
        if (kt + 1 < KT) {
            async16(ApA, Apf + ldsb0); async16(ApB, Apf + ldsb1);
            async16(BpA, Bpf + ldsb0); async16(BpB, Bpf + ldsb1);
        }
        ApA += 32; ApB += 32; BpA += 32; BpB += 32;

        bf16x8 a[4], b[4];
#pragma unroll
        for (int i = 0; i < 4; ++i) {
            a[i] = *(const bf16x8*)(Ac + aoff[i]);
            b[i] = *(const bf16x8*)(Bc + boff[i]);
        }
#pragma unroll
        for (int i = 0; i < 4; ++i)
#pragma unroll
            for (int j = 0; j < 4; ++j)
                acc[i][j] = __builtin_amdgcn_mfma_f32_16x16x32_bf16(a[i], b[j], acc[i][j], 0, 0, 0);
    };

    for (int kt = 0; kt < KT; kt += 2) {
        body(kt,     As0, Bs0, As1, Bs1);
        body(kt + 1, As1, Bs1, As0, Bs0);
    }
}

// ---------------------------------------------------------------------------
// Flash attention (causal), S^T/O^T, max-free softmax, register-resident P.
// Block = 128 Q rows (4 waves x 32 t-cols), one (b,h).  K-tile = 64 rows.
// Balanced 1-D grid decode (complement schedule) + XCD pinning.
// ---------------------------------------------------------------------------
__global__ __launch_bounds__(256) void attn_kernel(
    const u16* __restrict__ Qb, const u16* __restrict__ Kb,
    const u16* __restrict__ Vtb, u16* __restrict__ Yb)
{
    __shared__ u16 SMA[16384];       // Ks0|Ks1|Vs0|Vs1 (4x8KB), reused by epilogue
    u16* Ks0 = SMA;
    u16* Ks1 = SMA + 4096;
    u16* Vs0 = SMA + 8192;
    u16* Vs1 = SMA + 12288;

    int id = blockIdx.x;
    int kk = id >> 8;                // 0..3
    int cc = id & 255;
    int jj = cc >> 6;                // 0..3
    int bh = cc & 63;
    int qt = (kk == 0) ? jj : (kk == 1) ? (15 - jj) : (kk == 2) ? (jj + 4) : (11 - jj);

    int tid = threadIdx.x, lane = tid & 63, w = tid >> 6;
    int quad = lane >> 4, l15 = lane & 15;
    int qbase = qt * 128;
    int b = bh >> 4, h = bh & 15;

    bf16x8 qf[2][2];
    {
        const u16* q0 = Qb + ((size_t)(b * T_ + qbase + w * 32 + l15)) * C_ + h * 64;
        qf[0][0] = *(const bf16x8*)(q0 + quad * 8);
        qf[0][1] = *(const bf16x8*)(q0 + 32 + quad * 8);
        const u16* q1 = q0 + 16 * C_;
        qf[1][0] = *(const bf16x8*)(q1 + quad * 8);
        qf[1][1] = *(const bf16x8*)(q1 + 32 + quad * 8);
    }

    int koff0[4], koff1[4], voff[4][4];
#pragma unroll
    for (int sblk = 0; sblk < 4; ++sblk) {
        int sr = sblk * 16 + l15;
        koff0[sblk] = (sr * 64 + ((quad + sr) & 7) * 8) * 2;
        koff1[sblk] = (sr * 64 + ((4 + quad + sr) & 7) * 8) * 2;
    }
#pragma unroll
    for (int n = 0; n < 4; ++n)
#pragma unroll
        for (int sblk = 0; sblk < 4; ++sblk) {
            int dr = n * 16 + l15;
            voff[n][sblk] = (dr * 64 + ((sblk * 2 + (quad >> 1) + dr) & 7) * 8 + (quad & 1) * 4) * 2;
        }

    float l_part[2] = {0.f, 0.f};
    f32x4 o_acc[2][4];
    const f32x4 z4 = {0.f, 0.f, 0.f, 0.f};
#pragma unroll
    for (int c = 0; c < 2; ++c)
#pragma unroll
        for (int n = 0; n < 4; ++n) o_acc[c][n] = z4;

    int cA = tid, cB = tid + 256;
    int sA = cA >> 3, sB = cB >> 3;
    int offA = (((cA & 7) - sA) & 7) * 8;
    int offB = (((cB & 7) - sB) & 7) * 8;
    const u16* Kbase = Kb + (size_t)(b * T_) * C_ + h * 64;
    const u16* Vbase = Vtb + (size_t)bh * D_ * T_;
    int ldsb0 = (w * 64) * 16, ldsb1 = (256 + w * 64) * 16;

    const int nst = 2 * qt + 2;

    const u16* kgpA = Kbase + (size_t)sA * C_ + offA;
    const u16* kgpB = Kbase + (size_t)sB * C_ + offB;
    const u16* vgpA = Vbase + sA * T_ + offA;
    const u16* vgpB = Vbase + sB * T_ + offB;

    async16(kgpA, (char*)Ks0 + ldsb0);
    async16(kgpB, (char*)Ks0 + ldsb1);
    async16(vgpA, (char*)Vs0 + ldsb0);
    async16(vgpB, (char*)Vs0 + ldsb1);
    kgpA += 64 * C_; kgpB += 64 * C_; vgpA += 64; vgpB += 64;

    auto tile_body = [&](int st, const u16* K_, const u16* V_, char* Kpf, char* Vpf) {
        __syncthreads();
        if (st + 1 < nst) {
            async16(kgpA, Kpf + ldsb0);
            async16(kgpB, Kpf + ldsb1);
            async16(vgpA, Vpf + ldsb0);
            async16(vgpB, Vpf + ldsb1);
        }
        kgpA += 64 * C_; kgpB += 64 * C_; vgpA += 64; vgpB += 64;

        f32x4 sv[2][4];
#pragma unroll
        for (int sblk = 0; sblk < 4; ++sblk) {
            bf16x8 k0 = *(const bf16x8*)((const char*)K_ + koff0[sblk]);
            bf16x8 k1 = *(const bf16x8*)((const char*)K_ + koff1[sblk]);
#pragma unroll
            for (int c = 0; c < 2; ++c) {
                f32x4 t0 = __builtin_amdgcn_mfma_f32_16x16x32_bf16(k0, qf[c][0], z4, 0, 0, 0);
                sv[c][sblk] = __builtin_amdgcn_mfma_f32_16x16x32_bf16(k1, qf[c][1], t0, 0, 0, 0);
            }
        }

        if (st >= 2 * qt) {
            int sb0 = st * 64 - qbase;
#pragma unroll
            for (int c = 0; c < 2; ++c) {
                int tl = w * 32 + c * 16 + l15;
#pragma unroll
                for (int sblk = 0; sblk < 4; ++sblk)
#pragma unroll
                    for (int r = 0; r < 4; ++r)
                        if (sb0 + sblk * 16 + quad * 4 + r > tl) sv[c][sblk][r] = -1e30f;
            }
        }

        s16x4 pfrag[2][4];
#pragma unroll
        for (int c = 0; c < 2; ++c) {
            f32x4 s4 = z4;
#pragma unroll
            for (int sblk = 0; sblk < 4; ++sblk) {
#pragma unroll
                for (int r = 0; r < 4; ++r)
                    sv[c][sblk][r] = __builtin_amdgcn_exp2f(sv[c][sblk][r]);
                s4 += sv[c][sblk];
                uint2 pk;
                pk.x = pk_bf16(sv[c][sblk][0], sv[c][sblk][1]);
                pk.y = pk_bf16(sv[c][sblk][2], sv[c][sblk][3]);
                pfrag[c][sblk] = *(s16x4*)&pk;
            }
            l_part[c] += (s4[0] + s4[1]) + (s4[2] + s4[3]);
        }

#pragma unroll
        for (int n = 0; n < 4; ++n)
#pragma unroll
            for (int sblk = 0; sblk < 4; ++sblk) {
                s16x4 va = *(const s16x4*)((const char*)V_ + voff[n][sblk]);
#pragma unroll
                for (int c = 0; c < 2; ++c)
                    o_acc[c][n] = __builtin_amdgcn_mfma_f32_16x16x16bf16_1k(va, pfrag[c][sblk], o_acc[c][n], 0, 0, 0);
            }
    };

    for (int st = 0; st < nst; st += 2) {
        tile_body(st,     Ks0, Vs0, (char*)Ks1, (char*)Vs1);
        tile_body(st + 1, Ks1, Vs1, (char*)Ks0, (char*)Vs0);
    }

    // epilogue: LDS transpose (wave-private region, stride 72) -> coalesced
    __syncthreads();
    u16* PW = SMA + w * 2304;
#pragma unroll
    for (int c = 0; c < 2; ++c) {
        float l = l_part[c];
        l += __shfl_xor(l, 16, 64);
        l += __shfl_xor(l, 32, 64);
        float inv = 1.0f / l;
#pragma unroll
        for (int n = 0; n < 4; ++n) {
            u16x4 v;
            uint2 pk;
            pk.x = pk_bf16(o_acc[c][n][0] * inv, o_acc[c][n][1] * inv);
            pk.y = pk_bf16(o_acc[c][n][2] * inv, o_acc[c][n][3] * inv);
            v = *(u16x4*)&pk;
            *(u16x4*)&PW[(c * 16 + l15) * 72 + n * 16 + quad * 4] = v;
        }
    }
    asm volatile("s_waitcnt lgkmcnt(0)" ::: "memory");
#pragma unroll
    for (int st = 0; st < 4; ++st) {
        int tr = st * 8 + (lane >> 3);
        int d8 = (lane & 7) * 8;
        u16x8 v = *(u16x8*)&PW[tr * 72 + d8];
        *(u16x8*)&Yb[(size_t)(b * T_ + qbase + w * 32 + tr) * C_ + h * 64 + d8] = v;
    }
}

// ---------------------------------------------------------------------------
// Output projection, XCD-pinned 1-D grid (512 blocks), C^T orientation.
// Epilogue: fp32 LDS transpose in 2 ch-halves (stride 68) -> float4 stores.
// ---------------------------------------------------------------------------
__global__ __launch_bounds__(256, 4) void proj_gemm(
    const u16* __restrict__ Yb, const u16* __restrict__ Wob,
    const float* __restrict__ bo, float* __restrict__ out)
{
    __shared__ u16 SM[17408];
    u16* As = SM;
    u16* Bs = SM + 8192;

    int id = blockIdx.x;
    int xcd = id & 7;
    int local = id >> 3;
    int by = xcd * 8 + (local & 7);
    int bx = local >> 3;
    int m0 = bx * 128, n0 = by * 128;

    f32x4 acc[4][4];
    const f32x4 z4 = {0.f, 0.f, 0.f, 0.f};
#pragma unroll
    for (int i = 0; i < 4; ++i)
#pragma unroll
        for (int j = 0; j < 4; ++j) acc[i][j] = z4;

    gemm_core_128_db(Wob, Yb, As, Bs, m0, n0, acc);

    int lane = threadIdx.x & 63, w = threadIdx.x >> 6;
    int quad = lane >> 4, l15 = lane & 15;
    int wm = w >> 1, wn = w & 1;

    float* LF = (float*)SM;
    __syncthreads();
#pragma unroll
    for (int hh = 0; hh < 2; ++hh) {
        if (wm == hh) {
#pragma unroll
            for (int i = 0; i < 4; ++i) {
                int chl = i * 16 + quad * 4;
#pragma unroll
                for (int j = 0; j < 4; ++j) {
                    int tl = wn * 64 + j * 16 + l15;
                    *(f32x4*)&LF[tl * 68 + chl] = acc[i][j];
                }
            }
        }
        __syncthreads();
        f32x4 b4 = *(const f32x4*)&bo[m0 + hh * 64 + (lane & 15) * 4];
#pragma unroll
        for (int st = 0; st < 8; ++st) {
            int tl = w * 32 + st * 4 + (lane >> 4);
            int ch4 = (lane & 15) * 4;
            f32x4 v = *(f32x4*)&LF[tl * 68 + ch4];
            v += b4;
            *(f32x4*)&out[(size_t)(n0 + tl) * C_ + m0 + hh * 64 + ch4] = v;
        }
        if (hh == 0) __syncthreads();
    }
}

// ---------------------------------------------------------------------------
// launch
// ---------------------------------------------------------------------------
extern "C" void kernel_launch(void* const* d_in, const int* in_sizes, int n_in,
                              void* d_out, int out_size, void* d_ws, size_t ws_size,
                              hipStream_t stream) {
    const float* X  = (const float*)d_in[0];
    const float* Wq = (const float*)d_in[1];
    const float* Wk = (const float*)d_in[2];
    const float* Wv = (const float*)d_in[3];
    const float* Wo = (const float*)d_in[4];
    const float* bo = (const float*)d_in[5];

    char* ws = (char*)d_ws;
    u16* Xb  = (u16*)(ws);                       // 16 MB  [BT, C] bf16
    u16* Wqb = (u16*)(ws + (16u << 20));         //  2 MB
    u16* Wkb = (u16*)(ws + (18u << 20));         //  2 MB
    u16* Wvb = (u16*)(ws + (20u << 20));         //  2 MB
    u16* Wob = (u16*)(ws + (22u << 20));         //  2 MB
    u16* Qb  = (u16*)(ws + (24u << 20));         // 16 MB  [BT, C] (pre-scaled)
    u16* Kb  = (u16*)(ws + (40u << 20));         // 16 MB  [BT, C]
    u16* Vtb = (u16*)(ws + (56u << 20));         // 16 MB  [B,H,D,T]
    u16* Yb  = (u16*)(ws + (72u << 20));         // 16 MB  [BT, C]

    cast_bf16_kernel<<<(BT_ * C_ / 4) / 256, 256, 0, stream>>>(X, Xb, BT_ * C_ / 4);
    cast_w4_kernel<<<dim3((C_ * C_ / 4) / 256, 4), 256, 0, stream>>>(
        Wq, Wk, Wv, Wo, Wqb, Wkb, Wvb, Wob);

    qkv_gemm<<<dim3(512), 256, 0, stream>>>(Xb, Wqb, Wkb, Wvb, Qb, Kb, Vtb);
    attn_kernel<<<dim3((T_ / 128) * B_ * H_), 256, 0, stream>>>(Qb, Kb, Vtb, Yb);
    proj_gemm<<<dim3(8 * 64), 256, 0, stream>>>(Yb, Wob, bo, (float*)d_out);
}

// Round 10
// 262.755 us; speedup vs baseline: 1.0872x; 1.0050x over previous
//
#include <hip/hip_runtime.h>
#include <hip/hip_bf16.h>
#include <stdint.h>

// ---------------------------------------------------------------------------
// SplitCausalSelfAttention on MI355X (gfx950), bf16 MFMA implementation.
// B=4, T=2048, C=1024, H=16, D=64.
// R10: attention rebalanced to uniform-work blocks: grid 512, each block
//      runs the causal pair (qt=j, qt=15-j) sequentially = exactly 34
//      tile-units/block, so all blocks finish together (was: qt=15 block ran
//      a 32-unit solo tail -> 16% occupancy).  Same-bh pairing on each CU
//      preserves K/V L2 + XCD pinning.  Softmax denominator l now computed
//      by an extra ones-A MFMA per P-frag (sum moves from the exp2-saturated
//      VALU pipe to the 30%-busy MFMA pipe; no cross-lane reduction left).
//      qkv (fused, R9) and proj unchanged.
// ---------------------------------------------------------------------------

typedef unsigned short u16;
typedef __attribute__((ext_vector_type(8))) __bf16 bf16x8;  // 4 VGPRs (A/B frag, K=32)
typedef __attribute__((ext_vector_type(4))) float  f32x4;   // C/D frag
typedef __attribute__((ext_vector_type(4))) unsigned short u16x4;
typedef __attribute__((ext_vector_type(8))) unsigned short u16x8;
typedef __attribute__((ext_vector_type(4))) short s16x4;    // 2 VGPRs (A/B frag, K=16)

#define B_  4
#define T_  2048
#define C_  1024
#define H_  16
#define D_  64
#define BT_ (B_ * T_)

// scale = 1/sqrt(D) folded with log2(e) so softmax uses exp2
#define Q_SCALE 0.1803368801111204f

__device__ __forceinline__ u16 f32_to_bf16(float f) {
    unsigned int u = __float_as_uint(f);
    unsigned int r = (u + 0x7FFFu + ((u >> 16) & 1u)) >> 16;
    return (u16)r;
}

__device__ __forceinline__ unsigned int pk_bf16(float a, float b) {
    float2 f2; f2.x = a; f2.y = b;
    __hip_bfloat162 h = __float22bfloat162_rn(f2);
    return *(unsigned int*)&h;
}

__device__ __forceinline__ void async16(const void* g, void* lds) {
    __builtin_amdgcn_global_load_lds(
        (const __attribute__((address_space(1))) void*)g,
        (__attribute__((address_space(3))) void*)lds, 16, 0, 0);
}

// ---------------------------------------------------------------------------
// casts fp32 -> bf16
// ---------------------------------------------------------------------------
__global__ void cast_bf16_kernel(const float* __restrict__ in, u16* __restrict__ out, int n4) {
    int i = blockIdx.x * 256 + threadIdx.x;
    if (i >= n4) return;
    float4 v = ((const float4*)in)[i];
    u16x4 o;
    o[0] = f32_to_bf16(v.x); o[1] = f32_to_bf16(v.y);
    o[2] = f32_to_bf16(v.z); o[3] = f32_to_bf16(v.w);
    ((u16x4*)out)[i] = o;
}

__global__ void cast_w4_kernel(const float* __restrict__ w0, const float* __restrict__ w1,
                               const float* __restrict__ w2, const float* __restrict__ w3,
                               u16* __restrict__ o0, u16* __restrict__ o1,
                               u16* __restrict__ o2, u16* __restrict__ o3) {
    int which = blockIdx.y;
    const float* in = (which == 0) ? w0 : (which == 1) ? w1 : (which == 2) ? w2 : w3;
    u16* out = (which == 0) ? o0 : (which == 1) ? o1 : (which == 2) ? o2 : o3;
    int i = blockIdx.x * 256 + threadIdx.x;
    float4 v = ((const float4*)in)[i];
    u16x4 o;
    o[0] = f32_to_bf16(v.x); o[1] = f32_to_bf16(v.y);
    o[2] = f32_to_bf16(v.z); o[3] = f32_to_bf16(v.w);
    ((u16x4*)out)[i] = o;
}

// ---------------------------------------------------------------------------
// Fused QKV GEMM (R9).  Grid 512 = 64 t-tiles (XCD-pinned) x 8 ch-tiles.
// Per block: 128t x 128ch of Q, K, V.  K-loop BK=32, double-buffered,
// staging X + Wq + Wk + Wv tiles, 48 MFMA/wave/iter.
// ---------------------------------------------------------------------------
__global__ __launch_bounds__(256, 2) void qkv_gemm(
    const u16* __restrict__ Xb,
    const u16* __restrict__ Wqb, const u16* __restrict__ Wkb, const u16* __restrict__ Wvb,
    u16* __restrict__ Qb, u16* __restrict__ Kb, u16* __restrict__ Vtb)
{
    __shared__ u16 Xs[8192];         // 2 x 8KB halves
    __shared__ u16 Wqs[8192], Wks[8192], Wvs[8192];

    int id = blockIdx.x;
    int xcd = id & 7;
    int local = id >> 3;             // 0..63
    int tt = xcd * 8 + (local & 7);  // t tile 0..63 (XCD-pinned X slice)
    int ct = local >> 3;             // ch tile 0..7
    int m0 = tt * 128, n0 = ct * 128;

    int tid = threadIdx.x, lane = tid & 63, w = tid >> 6;
    int quad = lane >> 4, l15 = lane & 15;
    int wm = w >> 1, wn = w & 1;

    int c0 = tid, c1 = tid + 256;
    int row0 = c0 >> 2, row1 = c1 >> 2;
    int gc0 = (((c0 & 3) - (row0 >> 1)) & 3) * 8;
    int gc1 = (((c1 & 3) - (row1 >> 1)) & 3) * 8;
    int ldsb0 = (w * 64) * 16;
    int ldsb1 = (256 + w * 64) * 16;

    const u16* xp0 = Xb  + (size_t)(m0 + row0) * C_ + gc0;
    const u16* xp1 = Xb  + (size_t)(m0 + row1) * C_ + gc1;
    const u16* wq0 = Wqb + (size_t)(n0 + row0) * C_ + gc0;
    const u16* wq1 = Wqb + (size_t)(n0 + row1) * C_ + gc1;
    const u16* wk0 = Wkb + (size_t)(n0 + row0) * C_ + gc0;
    const u16* wk1 = Wkb + (size_t)(n0 + row1) * C_ + gc1;
    const u16* wv0 = Wvb + (size_t)(n0 + row0) * C_ + gc0;
    const u16* wv1 = Wvb + (size_t)(n0 + row1) * C_ + gc1;

    int aoff[4], boff[4];
#pragma unroll
    for (int i = 0; i < 4; ++i) {
        int rA = wm * 64 + i * 16 + l15;
        aoff[i] = (rA * 32 + (((rA >> 1) + quad) & 3) * 8) * 2;
        int rB = wn * 64 + i * 16 + l15;
        boff[i] = (rB * 32 + (((rB >> 1) + quad) & 3) * 8) * 2;
    }

    f32x4 aq[4][4], ak[4][4], av[4][4];   // [Afrag][Bfrag]
    const f32x4 z4 = {0.f, 0.f, 0.f, 0.f};
#pragma unroll
    for (int i = 0; i < 4; ++i)
#pragma unroll
        for (int j = 0; j < 4; ++j) { aq[i][j] = z4; ak[i][j] = z4; av[i][j] = z4; }

    async16(xp0, (char*)Xs  + ldsb0); async16(xp1, (char*)Xs  + ldsb1);
    async16(wq0, (char*)Wqs + ldsb0); async16(wq1, (char*)Wqs + ldsb1);
    async16(wk0, (char*)Wks + ldsb0); async16(wk1, (char*)Wks + ldsb1);
    async16(wv0, (char*)Wvs + ldsb0); async16(wv1, (char*)Wvs + ldsb1);
    xp0 += 32; xp1 += 32; wq0 += 32; wq1 += 32;
    wk0 += 32; wk1 += 32; wv0 += 32; wv1 += 32;

    auto body = [&](int kt, int cur, int nxt) {
        __syncthreads();
        if (kt + 1 < 32) {
            async16(xp0, (char*)Xs  + nxt + ldsb0); async16(xp1, (char*)Xs  + nxt + ldsb1);
            async16(wq0, (char*)Wqs + nxt + ldsb0); async16(wq1, (char*)Wqs + nxt + ldsb1);
            async16(wk0, (char*)Wks + nxt + ldsb0); async16(wk1, (char*)Wks + nxt + ldsb1);
            async16(wv0, (char*)Wvs + nxt + ldsb0); async16(wv1, (char*)Wvs + nxt + ldsb1);
        }
        xp0 += 32; xp1 += 32; wq0 += 32; wq1 += 32;
        wk0 += 32; wk1 += 32; wv0 += 32; wv1 += 32;

        bf16x8 xa[4];
#pragma unroll
        for (int i = 0; i < 4; ++i)
            xa[i] = *(const bf16x8*)((const char*)Xs + cur + aoff[i]);

        bf16x8 bb[4];
#pragma unroll
        for (int j = 0; j < 4; ++j)
            bb[j] = *(const bf16x8*)((const char*)Wqs + cur + boff[j]);
#pragma unroll
        for (int j = 0; j < 4; ++j)
#pragma unroll
            for (int i = 0; i < 4; ++i)
                aq[j][i] = __builtin_amdgcn_mfma_f32_16x16x32_bf16(bb[j], xa[i], aq[j][i], 0, 0, 0);

#pragma unroll
        for (int j = 0; j < 4; ++j)
            bb[j] = *(const bf16x8*)((const char*)Wks + cur + boff[j]);
#pragma unroll
        for (int j = 0; j < 4; ++j)
#pragma unroll
            for (int i = 0; i < 4; ++i)
                ak[j][i] = __builtin_amdgcn_mfma_f32_16x16x32_bf16(bb[j], xa[i], ak[j][i], 0, 0, 0);

#pragma unroll
        for (int j = 0; j < 4; ++j)
            bb[j] = *(const bf16x8*)((const char*)Wvs + cur + boff[j]);
#pragma unroll
        for (int i = 0; i < 4; ++i)
#pragma unroll
            for (int j = 0; j < 4; ++j)
                av[i][j] = __builtin_amdgcn_mfma_f32_16x16x32_bf16(xa[i], bb[j], av[i][j], 0, 0, 0);
    };

    for (int kt = 0; kt < 32; kt += 2) {
        body(kt,     0,    8192);
        body(kt + 1, 8192, 0);
    }

    // Q/K epilogue (C^T): lane holds 4 consecutive channels at fixed t
#pragma unroll
    for (int j = 0; j < 4; ++j) {
        int ch0 = n0 + wn * 64 + j * 16 + quad * 4;
#pragma unroll
        for (int i = 0; i < 4; ++i) {
            int t = m0 + wm * 64 + i * 16 + l15;
            u16x4 vq, vk;
#pragma unroll
            for (int r = 0; r < 4; ++r) {
                vq[r] = f32_to_bf16(aq[j][i][r] * Q_SCALE);
                vk[r] = f32_to_bf16(ak[j][i][r]);
            }
            *(u16x4*)&Qb[(size_t)t * C_ + ch0] = vq;
            *(u16x4*)&Kb[(size_t)t * C_ + ch0] = vk;
        }
    }
    // V epilogue (C): lane holds 4 consecutive t at fixed channel -> [B,H,D,T]
#pragma unroll
    for (int i = 0; i < 4; ++i) {
        int t0 = m0 + wm * 64 + i * 16 + quad * 4;
        int bb_ = t0 >> 11, tloc = t0 & (T_ - 1);
#pragma unroll
        for (int j = 0; j < 4; ++j) {
            int col = n0 + wn * 64 + j * 16 + l15;
            int h = col >> 6, d = col & 63;
            u16x4 v;
#pragma unroll
            for (int r = 0; r < 4; ++r) v[r] = f32_to_bf16(av[i][j][r]);
            *(u16x4*)&Vtb[(((bb_ * H_ + h) * D_ + d) * T_) + tloc] = v;
        }
    }
}

// ---------------------------------------------------------------------------
// GEMM core, double-buffered (used by proj).
// ---------------------------------------------------------------------------
__device__ __forceinline__ void gemm_core_128_db(
    const u16* __restrict__ A, const u16* __restrict__ B,
    u16* As, u16* Bs, int m0, int n0, f32x4 (&acc)[4][4])
{
    const int K = C_;
    const int KT = K / 32;
    int tid  = threadIdx.x;
    int lane = tid & 63, w = tid >> 6;
    int quad = lane >> 4, l15 = lane & 15;
    int wm = w >> 1, wn = w & 1;

    int c0 = tid, c1 = tid + 256;
    int row0 = c0 >> 2, row1 = c1 >> 2;
    int gc0 = (((c0 & 3) - (row0 >> 1)) & 3) * 8;
    int gc1 = (((c1 & 3) - (row1 >> 1)) & 3) * 8;
    int ldsb0 = (w * 64) * 16;
    int ldsb1 = (256 + w * 64) * 16;

    const u16* ApA = A + (size_t)(m0 + row0) * K + gc0;
    const u16* ApB = A + (size_t)(m0 + row1) * K + gc1;
    const u16* BpA = B + (size_t)(n0 + row0) * K + gc0;
    const u16* BpB = B + (size_t)(n0 + row1) * K + gc1;

    char* As0 = (char*)As; char* As1 = (char*)As + 8192;
    char* Bs0 = (char*)Bs; char* Bs1 = (char*)Bs + 8192;

    int aoff[4], boff[4];
#pragma unroll
    for (int i = 0; i < 4; ++i) {
        int rA = wm * 64 + i * 16 + l15;
        aoff[i] = (rA * 32 + (((rA >> 1) + quad) & 3) * 8) * 2;
        int rB = wn * 64 + i * 16 + l15;
        boff[i] = (rB * 32 + (((rB >> 1) + quad) & 3) * 8) * 2;
    }

    async16(ApA, As0 + ldsb0); async16(ApB, As0 + ldsb1);
    async16(BpA, Bs0 + ldsb0); async16(BpB, Bs0 + ldsb1);
    ApA += 32; ApB += 32; BpA += 32; BpB += 32;

    auto body = [&](int kt, const char* Ac, const char* Bc, char* Apf, char* Bpf) {
        __syncthreads();
        if (kt + 1 < KT) {
            async16(ApA, Apf + ldsb0); async16(ApB, Apf + ldsb1);
            async16(BpA, Bpf + ldsb0); async16(BpB, Bpf + ldsb1);
        }
        ApA += 32; ApB += 32; BpA += 32; BpB += 32;

        bf16x8 a[4], b[4];
#pragma unroll
        for (int i = 0; i < 4; ++i) {
            a[i] = *(const bf16x8*)(Ac + aoff[i]);
            b[i] = *(const bf16x8*)(Bc + boff[i]);
        }
#pragma unroll
        for (int i = 0; i < 4; ++i)
#pragma unroll
            for (int j = 0; j < 4; ++j)
                acc[i][j] = __builtin_amdgcn_mfma_f32_16x16x32_bf16(a[i], b[j], acc[i][j], 0, 0, 0);
    };

    for (int kt = 0; kt < KT; kt += 2) {
        body(kt,     As0, Bs0, As1, Bs1);
        body(kt + 1, As1, Bs1, As0, Bs0);
    }
}

// ---------------------------------------------------------------------------
// Flash attention (causal), S^T/O^T, max-free softmax, register-resident P.
// R10 grid: 512 blocks = 8 pairs x 64 bh.  Block (j, bh) processes
// qt=j then qt=15-j sequentially -> exactly 34 tile-units per block.
// id%256 pairing puts (j, j+4) of the SAME bh on one CU (K/V L2 reuse);
// id%8 == bh%8 pins each bh to one XCD.
// l computed via ones-A MFMA (no VALU sums, no shfl reduction).
// ---------------------------------------------------------------------------
__global__ __launch_bounds__(256) void attn_kernel(
    const u16* __restrict__ Qb, const u16* __restrict__ Kb,
    const u16* __restrict__ Vtb, u16* __restrict__ Yb)
{
    __shared__ u16 SMA[16384];       // Ks0|Ks1|Vs0|Vs1 (4x8KB), reused by epilogue
    u16* Ks0 = SMA;
    u16* Ks1 = SMA + 4096;
    u16* Vs0 = SMA + 8192;
    u16* Vs1 = SMA + 12288;

    int id = blockIdx.x;
    int bh = id & 63;
    int jj = id >> 6;                // 0..7

    int tid = threadIdx.x, lane = tid & 63, w = tid >> 6;
    int quad = lane >> 4, l15 = lane & 15;
    int b = bh >> 4, h = bh & 15;

    // loop-invariant LDS byte offsets (K: 8 x b128, V: 16 x b64)
    int koff0[4], koff1[4], voff[4][4];
#pragma unroll
    for (int sblk = 0; sblk < 4; ++sblk) {
        int sr = sblk * 16 + l15;
        koff0[sblk] = (sr * 64 + ((quad + sr) & 7) * 8) * 2;
        koff1[sblk] = (sr * 64 + ((4 + quad + sr) & 7) * 8) * 2;
    }
#pragma unroll
    for (int n = 0; n < 4; ++n)
#pragma unroll
        for (int sblk = 0; sblk < 4; ++sblk) {
            int dr = n * 16 + l15;
            voff[n][sblk] = (dr * 64 + ((sblk * 2 + (quad >> 1) + dr) & 7) * 8 + (quad & 1) * 4) * 2;
        }

    // staging chunk assignment (512 chunks of 16B per 8KB tile, 2 passes)
    int cA = tid, cB = tid + 256;
    int sA = cA >> 3, sB = cB >> 3;
    int offA = (((cA & 7) - sA) & 7) * 8;
    int offB = (((cB & 7) - sB) & 7) * 8;
    const u16* Kbase = Kb + (size_t)(b * T_) * C_ + h * 64;
    const u16* Vbase = Vtb + (size_t)bh * D_ * T_;
    int ldsb0 = (w * 64) * 16, ldsb1 = (256 + w * 64) * 16;

    const s16x4 ones = { (short)0x3F80, (short)0x3F80, (short)0x3F80, (short)0x3F80 };
    const f32x4 z4 = {0.f, 0.f, 0.f, 0.f};

    int qts[2] = { jj, 15 - jj };

    for (int pass = 0; pass < 2; ++pass) {
        int qt = qts[pass];
        int qbase = qt * 128;

        if (pass) __syncthreads();   // prior epilogue LDS reads done

        // Q B-frags from [BT,C]: 2 col-groups x 2 k-halves
        bf16x8 qf[2][2];
        {
            const u16* q0 = Qb + ((size_t)(b * T_ + qbase + w * 32 + l15)) * C_ + h * 64;
            qf[0][0] = *(const bf16x8*)(q0 + quad * 8);
            qf[0][1] = *(const bf16x8*)(q0 + 32 + quad * 8);
            const u16* q1 = q0 + 16 * C_;
            qf[1][0] = *(const bf16x8*)(q1 + quad * 8);
            qf[1][1] = *(const bf16x8*)(q1 + 32 + quad * 8);
        }

        f32x4 o_acc[2][4];           // O^T: col t (l15), rows d=n*16+quad*4+r
        f32x4 l_acc[2];              // all 4 regs identical = sum_s P[s,t]
#pragma unroll
        for (int c = 0; c < 2; ++c) {
            l_acc[c] = z4;
#pragma unroll
            for (int n = 0; n < 4; ++n) o_acc[c][n] = z4;
        }

        const int nst = 2 * qt + 2;  // always even

        const u16* kgpA = Kbase + (size_t)sA * C_ + offA;
        const u16* kgpB = Kbase + (size_t)sB * C_ + offB;
        const u16* vgpA = Vbase + sA * T_ + offA;
        const u16* vgpB = Vbase + sB * T_ + offB;

        // prologue: stage tile 0 into buffer 0
        async16(kgpA, (char*)Ks0 + ldsb0);
        async16(kgpB, (char*)Ks0 + ldsb1);
        async16(vgpA, (char*)Vs0 + ldsb0);
        async16(vgpB, (char*)Vs0 + ldsb1);
        kgpA += 64 * C_; kgpB += 64 * C_; vgpA += 64; vgpB += 64;

        auto tile_body = [&](int st, const u16* K_, const u16* V_, char* Kpf, char* Vpf) {
            __syncthreads();   // tile st resident; prev reads done
            if (st + 1 < nst) {
                async16(kgpA, Kpf + ldsb0);
                async16(kgpB, Kpf + ldsb1);
                async16(vgpA, Vpf + ldsb0);
                async16(vgpB, Vpf + ldsb1);
            }
            kgpA += 64 * C_; kgpB += 64 * C_; vgpA += 64; vgpB += 64;

            // S^T = K Q^T : per wave 64(s) x 32(t), K frags shared across c
            f32x4 sv[2][4];
#pragma unroll
            for (int sblk = 0; sblk < 4; ++sblk) {
                bf16x8 k0 = *(const bf16x8*)((const char*)K_ + koff0[sblk]);
                bf16x8 k1 = *(const bf16x8*)((const char*)K_ + koff1[sblk]);
#pragma unroll
                for (int c = 0; c < 2; ++c) {
                    f32x4 t0 = __builtin_amdgcn_mfma_f32_16x16x32_bf16(k0, qf[c][0], z4, 0, 0, 0);
                    sv[c][sblk] = __builtin_amdgcn_mfma_f32_16x16x32_bf16(k1, qf[c][1], t0, 0, 0, 0);
                }
            }

            if (st >= 2 * qt) {   // diagonal region: causal mask (s > t)
                int sb0 = st * 64 - qbase;
#pragma unroll
                for (int c = 0; c < 2; ++c) {
                    int tl = w * 32 + c * 16 + l15;
#pragma unroll
                    for (int sblk = 0; sblk < 4; ++sblk)
#pragma unroll
                        for (int r = 0; r < 4; ++r)
                            if (sb0 + sblk * 16 + quad * 4 + r > tl) sv[c][sblk][r] = -1e30f;
                }
            }

            // max-free softmax: raw v_exp_f32, P packed to regs; l via ones-MFMA
            s16x4 pfrag[2][4];
#pragma unroll
            for (int c = 0; c < 2; ++c) {
#pragma unroll
                for (int sblk = 0; sblk < 4; ++sblk) {
#pragma unroll
                    for (int r = 0; r < 4; ++r)
                        sv[c][sblk][r] = __builtin_amdgcn_exp2f(sv[c][sblk][r]);
                    uint2 pk;
                    pk.x = pk_bf16(sv[c][sblk][0], sv[c][sblk][1]);
                    pk.y = pk_bf16(sv[c][sblk][2], sv[c][sblk][3]);
                    pfrag[c][sblk] = *(s16x4*)&pk;
                    l_acc[c] = __builtin_amdgcn_mfma_f32_16x16x16bf16_1k(ones, pfrag[c][sblk], l_acc[c], 0, 0, 0);
                }
            }

            // O^T += V^T P via mfma 16x16x16: A = V^T (LDS b64), B = pfrag
#pragma unroll
            for (int n = 0; n < 4; ++n)
#pragma unroll
                for (int sblk = 0; sblk < 4; ++sblk) {
                    s16x4 va = *(const s16x4*)((const char*)V_ + voff[n][sblk]);
#pragma unroll
                    for (int c = 0; c < 2; ++c)
                        o_acc[c][n] = __builtin_amdgcn_mfma_f32_16x16x16bf16_1k(va, pfrag[c][sblk], o_acc[c][n], 0, 0, 0);
                }
        };

        for (int st = 0; st < nst; st += 2) {
            tile_body(st,     Ks0, Vs0, (char*)Ks1, (char*)Vs1);
            tile_body(st + 1, Ks1, Vs1, (char*)Ks0, (char*)Vs0);
        }

        // epilogue: LDS transpose (wave-private, stride 72) -> coalesced stores
        __syncthreads();             // all waves done reading K/V LDS
        u16* PW = SMA + w * 2304;
#pragma unroll
        for (int c = 0; c < 2; ++c) {
            float inv = 1.0f / l_acc[c][0];   // all regs equal (ones-MFMA)
#pragma unroll
            for (int n = 0; n < 4; ++n) {
                u16x4 v;
                uint2 pk;
                pk.x = pk_bf16(o_acc[c][n][0] * inv, o_acc[c][n][1] * inv);
                pk.y = pk_bf16(o_acc[c][n][2] * inv, o_acc[c][n][3] * inv);
                v = *(u16x4*)&pk;
                *(u16x4*)&PW[(c * 16 + l15) * 72 + n * 16 + quad * 4] = v;
            }
        }
        asm volatile("s_waitcnt lgkmcnt(0)" ::: "memory");   // wave-private
#pragma unroll
        for (int st = 0; st < 4; ++st) {
            int tr = st * 8 + (lane >> 3);
            int d8 = (lane & 7) * 8;
            u16x8 v = *(u16x8*)&PW[tr * 72 + d8];
            *(u16x8*)&Yb[(size_t)(b * T_ + qbase + w * 32 + tr) * C_ + h * 64 + d8] = v;
        }
    }
}

// ---------------------------------------------------------------------------
// Output projection, XCD-pinned 1-D grid (512 blocks), C^T orientation.
// Epilogue: fp32 LDS transpose in 2 ch-halves (stride 68) -> float4 stores.
// ---------------------------------------------------------------------------
__global__ __launch_bounds__(256, 4) void proj_gemm(
    const u16* __restrict__ Yb, const u16* __restrict__ Wob,
    const float* __restrict__ bo, float* __restrict__ out)
{
    __shared__ u16 SM[17408];
    u16* As = SM;
    u16* Bs = SM + 8192;

    int id = blockIdx.x;
    int xcd = id & 7;
    int local = id >> 3;
    int by = xcd * 8 + (local & 7);
    int bx = local >> 3;
    int m0 = bx * 128, n0 = by * 128;

    f32x4 acc[4][4];
    const f32x4 z4 = {0.f, 0.f, 0.f, 0.f};
#pragma unroll
    for (int i = 0; i < 4; ++i)
#pragma unroll
        for (int j = 0; j < 4; ++j) acc[i][j] = z4;

    gemm_core_128_db(Wob, Yb, As, Bs, m0, n0, acc);

    int lane = threadIdx.x & 63, w = threadIdx.x >> 6;
    int quad = lane >> 4, l15 = lane & 15;
    int wm = w >> 1, wn = w & 1;

    float* LF = (float*)SM;
    __syncthreads();
#pragma unroll
    for (int hh = 0; hh < 2; ++hh) {
        if (wm == hh) {
#pragma unroll
            for (int i = 0; i < 4; ++i) {
                int chl = i * 16 + quad * 4;
#pragma unroll
                for (int j = 0; j < 4; ++j) {
                    int tl = wn * 64 + j * 16 + l15;
                    *(f32x4*)&LF[tl * 68 + chl] = acc[i][j];
                }
            }
        }
        __syncthreads();
        f32x4 b4 = *(const f32x4*)&bo[m0 + hh * 64 + (lane & 15) * 4];
#pragma unroll
        for (int st = 0; st < 8; ++st) {
            int tl = w * 32 + st * 4 + (lane >> 4);
            int ch4 = (lane & 15) * 4;
            f32x4 v = *(f32x4*)&LF[tl * 68 + ch4];
            v += b4;
            *(f32x4*)&out[(size_t)(n0 + tl) * C_ + m0 + hh * 64 + ch4] = v;
        }
        if (hh == 0) __syncthreads();
    }
}

// ---------------------------------------------------------------------------
// launch
// ---------------------------------------------------------------------------
extern "C" void kernel_launch(void* const* d_in, const int* in_sizes, int n_in,
                              void* d_out, int out_size, void* d_ws, size_t ws_size,
                              hipStream_t stream) {
    const float* X  = (const float*)d_in[0];
    const float* Wq = (const float*)d_in[1];
    const float* Wk = (const float*)d_in[2];
    const float* Wv = (const float*)d_in[3];
    const float* Wo = (const float*)d_in[4];
    const float* bo = (const float*)d_in[5];

    char* ws = (char*)d_ws;
    u16* Xb  = (u16*)(ws);                       // 16 MB  [BT, C] bf16
    u16* Wqb = (u16*)(ws + (16u << 20));         //  2 MB
    u16* Wkb = (u16*)(ws + (18u << 20));         //  2 MB
    u16* Wvb = (u16*)(ws + (20u << 20));         //  2 MB
    u16* Wob = (u16*)(ws + (22u << 20));         //  2 MB
    u16* Qb  = (u16*)(ws + (24u << 20));         // 16 MB  [BT, C] (pre-scaled)
    u16* Kb  = (u16*)(ws + (40u << 20));         // 16 MB  [BT, C]
    u16* Vtb = (u16*)(ws + (56u << 20));         // 16 MB  [B,H,D,T]
    u16* Yb  = (u16*)(ws + (72u << 20));         // 16 MB  [BT, C]

    cast_bf16_kernel<<<(BT_ * C_ / 4) / 256, 256, 0, stream>>>(X, Xb, BT_ * C_ / 4);
    cast_w4_kernel<<<dim3((C_ * C_ / 4) / 256, 4), 256, 0, stream>>>(
        Wq, Wk, Wv, Wo, Wqb, Wkb, Wvb, Wob);

    qkv_gemm<<<dim3(512), 256, 0, stream>>>(Xb, Wqb, Wkb, Wvb, Qb, Kb, Vtb);
    attn_kernel<<<dim3(512), 256, 0, stream>>>(Qb, Kb, Vtb, Yb);
    proj_gemm<<<dim3(8 * 64), 256, 0, stream>>>(Yb, Wob, bo, (float*)d_out);
}

// Round 11
// 258.196 us; speedup vs baseline: 1.1064x; 1.0177x over previous
//
#include <hip/hip_runtime.h>
#include <hip/hip_bf16.h>
#include <stdint.h>

// ---------------------------------------------------------------------------
// SplitCausalSelfAttention on MI355X (gfx950), bf16 MFMA implementation.
// B=4, T=2048, C=1024, H=16, D=64.
// R11: attention split to 64-row Q-tiles, grid 1024 = 16 uniform pairs
//      (qt=j, 31-j; 33 K-tiles each) x 64 bh -> 4 blocks/CU co-resident
//      (16 waves/CU, was 8).  Same-bh per CU preserves K/V L2 reuse; XCD
//      pin intact.  MFMA/exp2 totals unchanged.  Casts merged into ONE
//      kernel (one less launch boundary).  qkv (fused R9) and proj are at
//      the m97-structure plateau (718 TF) — unchanged.
// ---------------------------------------------------------------------------

typedef unsigned short u16;
typedef __attribute__((ext_vector_type(8))) __bf16 bf16x8;  // 4 VGPRs (A/B frag, K=32)
typedef __attribute__((ext_vector_type(4))) float  f32x4;   // C/D frag
typedef __attribute__((ext_vector_type(4))) unsigned short u16x4;
typedef __attribute__((ext_vector_type(8))) unsigned short u16x8;
typedef __attribute__((ext_vector_type(4))) short s16x4;    // 2 VGPRs (A/B frag, K=16)

#define B_  4
#define T_  2048
#define C_  1024
#define H_  16
#define D_  64
#define BT_ (B_ * T_)

// scale = 1/sqrt(D) folded with log2(e) so softmax uses exp2
#define Q_SCALE 0.1803368801111204f

__device__ __forceinline__ u16 f32_to_bf16(float f) {
    unsigned int u = __float_as_uint(f);
    unsigned int r = (u + 0x7FFFu + ((u >> 16) & 1u)) >> 16;
    return (u16)r;
}

__device__ __forceinline__ unsigned int pk_bf16(float a, float b) {
    float2 f2; f2.x = a; f2.y = b;
    __hip_bfloat162 h = __float22bfloat162_rn(f2);
    return *(unsigned int*)&h;
}

__device__ __forceinline__ void async16(const void* g, void* lds) {
    __builtin_amdgcn_global_load_lds(
        (const __attribute__((address_space(1))) void*)g,
        (__attribute__((address_space(3))) void*)lds, 16, 0, 0);
}

// ---------------------------------------------------------------------------
// single cast kernel: X (8192 blocks) + 4 weights (1024 blocks each)
// ---------------------------------------------------------------------------
__global__ void cast_all_kernel(const float* __restrict__ X,
                                const float* __restrict__ w0, const float* __restrict__ w1,
                                const float* __restrict__ w2, const float* __restrict__ w3,
                                u16* __restrict__ xo,
                                u16* __restrict__ o0, u16* __restrict__ o1,
                                u16* __restrict__ o2, u16* __restrict__ o3) {
    int id = blockIdx.x;
    const float* in; u16* out; int i;
    if (id < 8192) {
        in = X; out = xo; i = id * 256 + threadIdx.x;
    } else {
        int k = (id - 8192) >> 10;
        in  = (k == 0) ? w0 : (k == 1) ? w1 : (k == 2) ? w2 : w3;
        out = (k == 0) ? o0 : (k == 1) ? o1 : (k == 2) ? o2 : o3;
        i = ((id - 8192) & 1023) * 256 + threadIdx.x;
    }
    float4 v = ((const float4*)in)[i];
    u16x4 o;
    o[0] = f32_to_bf16(v.x); o[1] = f32_to_bf16(v.y);
    o[2] = f32_to_bf16(v.z); o[3] = f32_to_bf16(v.w);
    ((u16x4*)out)[i] = o;
}

// ---------------------------------------------------------------------------
// Fused QKV GEMM (R9).  Grid 512 = 64 t-tiles (XCD-pinned) x 8 ch-tiles.
// ---------------------------------------------------------------------------
__global__ __launch_bounds__(256, 2) void qkv_gemm(
    const u16* __restrict__ Xb,
    const u16* __restrict__ Wqb, const u16* __restrict__ Wkb, const u16* __restrict__ Wvb,
    u16* __restrict__ Qb, u16* __restrict__ Kb, u16* __restrict__ Vtb)
{
    __shared__ u16 Xs[8192];         // 2 x 8KB halves
    __shared__ u16 Wqs[8192], Wks[8192], Wvs[8192];

    int id = blockIdx.x;
    int xcd = id & 7;
    int local = id >> 3;             // 0..63
    int tt = xcd * 8 + (local & 7);  // t tile 0..63 (XCD-pinned X slice)
    int ct = local >> 3;             // ch tile 0..7
    int m0 = tt * 128, n0 = ct * 128;

    int tid = threadIdx.x, lane = tid & 63, w = tid >> 6;
    int quad = lane >> 4, l15 = lane & 15;
    int wm = w >> 1, wn = w & 1;

    int c0 = tid, c1 = tid + 256;
    int row0 = c0 >> 2, row1 = c1 >> 2;
    int gc0 = (((c0 & 3) - (row0 >> 1)) & 3) * 8;
    int gc1 = (((c1 & 3) - (row1 >> 1)) & 3) * 8;
    int ldsb0 = (w * 64) * 16;
    int ldsb1 = (256 + w * 64) * 16;

    const u16* xp0 = Xb  + (size_t)(m0 + row0) * C_ + gc0;
    const u16* xp1 = Xb  + (size_t)(m0 + row1) * C_ + gc1;
    const u16* wq0 = Wqb + (size_t)(n0 + row0) * C_ + gc0;
    const u16* wq1 = Wqb + (size_t)(n0 + row1) * C_ + gc1;
    const u16* wk0 = Wkb + (size_t)(n0 + row0) * C_ + gc0;
    const u16* wk1 = Wkb + (size_t)(n0 + row1) * C_ + gc1;
    const u16* wv0 = Wvb + (size_t)(n0 + row0) * C_ + gc0;
    const u16* wv1 = Wvb + (size_t)(n0 + row1) * C_ + gc1;

    int aoff[4], boff[4];
#pragma unroll
    for (int i = 0; i < 4; ++i) {
        int rA = wm * 64 + i * 16 + l15;
        aoff[i] = (rA * 32 + (((rA >> 1) + quad) & 3) * 8) * 2;
        int rB = wn * 64 + i * 16 + l15;
        boff[i] = (rB * 32 + (((rB >> 1) + quad) & 3) * 8) * 2;
    }

    f32x4 aq[4][4], ak[4][4], av[4][4];   // [Afrag][Bfrag]
    const f32x4 z4 = {0.f, 0.f, 0.f, 0.f};
#pragma unroll
    for (int i = 0; i < 4; ++i)
#pragma unroll
        for (int j = 0; j < 4; ++j) { aq[i][j] = z4; ak[i][j] = z4; av[i][j] = z4; }

    async16(xp0, (char*)Xs  + ldsb0); async16(xp1, (char*)Xs  + ldsb1);
    async16(wq0, (char*)Wqs + ldsb0); async16(wq1, (char*)Wqs + ldsb1);
    async16(wk0, (char*)Wks + ldsb0); async16(wk1, (char*)Wks + ldsb1);
    async16(wv0, (char*)Wvs + ldsb0); async16(wv1, (char*)Wvs + ldsb1);
    xp0 += 32; xp1 += 32; wq0 += 32; wq1 += 32;
    wk0 += 32; wk1 += 32; wv0 += 32; wv1 += 32;

    auto body = [&](int kt, int cur, int nxt) {
        __syncthreads();
        if (kt + 1 < 32) {
            async16(xp0, (char*)Xs  + nxt + ldsb0); async16(xp1, (char*)Xs  + nxt + ldsb1);
            async16(wq0, (char*)Wqs + nxt + ldsb0); async16(wq1, (char*)Wqs + nxt + ldsb1);
            async16(wk0, (char*)Wks + nxt + ldsb0); async16(wk1, (char*)Wks + nxt + ldsb1);
            async16(wv0, (char*)Wvs + nxt + ldsb0); async16(wv1, (char*)Wvs + nxt + ldsb1);
        }
        xp0 += 32; xp1 += 32; wq0 += 32; wq1 += 32;
        wk0 += 32; wk1 += 32; wv0 += 32; wv1 += 32;

        bf16x8 xa[4];
#pragma unroll
        for (int i = 0; i < 4; ++i)
            xa[i] = *(const bf16x8*)((const char*)Xs + cur + aoff[i]);

        bf16x8 bb[4];
#pragma unroll
        for (int j = 0; j < 4; ++j)
            bb[j] = *(const bf16x8*)((const char*)Wqs + cur + boff[j]);
#pragma unroll
        for (int j = 0; j < 4; ++j)
#pragma unroll
            for (int i = 0; i < 4; ++i)
                aq[j][i] = __builtin_amdgcn_mfma_f32_16x16x32_bf16(bb[j], xa[i], aq[j][i], 0, 0, 0);

#pragma unroll
        for (int j = 0; j < 4; ++j)
            bb[j] = *(const bf16x8*)((const char*)Wks + cur + boff[j]);
#pragma unroll
        for (int j = 0; j < 4; ++j)
#pragma unroll
            for (int i = 0; i < 4; ++i)
                ak[j][i] = __builtin_amdgcn_mfma_f32_16x16x32_bf16(bb[j], xa[i], ak[j][i], 0, 0, 0);

#pragma unroll
        for (int j = 0; j < 4; ++j)
            bb[j] = *(const bf16x8*)((const char*)Wvs + cur + boff[j]);
#pragma unroll
        for (int i = 0; i < 4; ++i)
#pragma unroll
            for (int j = 0; j < 4; ++j)
                av[i][j] = __builtin_amdgcn_mfma_f32_16x16x32_bf16(xa[i], bb[j], av[i][j], 0, 0, 0);
    };

    for (int kt = 0; kt < 32; kt += 2) {
        body(kt,     0,    8192);
        body(kt + 1, 8192, 0);
    }

    // Q/K epilogue (C^T): lane holds 4 consecutive channels at fixed t
#pragma unroll
    for (int j = 0; j < 4; ++j) {
        int ch0 = n0 + wn * 64 + j * 16 + quad * 4;
#pragma unroll
        for (int i = 0; i < 4; ++i) {
            int t = m0 + wm * 64 + i * 16 + l15;
            u16x4 vq, vk;
#pragma unroll
            for (int r = 0; r < 4; ++r) {
                vq[r] = f32_to_bf16(aq[j][i][r] * Q_SCALE);
                vk[r] = f32_to_bf16(ak[j][i][r]);
            }
            *(u16x4*)&Qb[(size_t)t * C_ + ch0] = vq;
            *(u16x4*)&Kb[(size_t)t * C_ + ch0] = vk;
        }
    }
    // V epilogue (C): lane holds 4 consecutive t at fixed channel -> [B,H,D,T]
#pragma unroll
    for (int i = 0; i < 4; ++i) {
        int t0 = m0 + wm * 64 + i * 16 + quad * 4;
        int bb_ = t0 >> 11, tloc = t0 & (T_ - 1);
#pragma unroll
        for (int j = 0; j < 4; ++j) {
            int col = n0 + wn * 64 + j * 16 + l15;
            int h = col >> 6, d = col & 63;
            u16x4 v;
#pragma unroll
            for (int r = 0; r < 4; ++r) v[r] = f32_to_bf16(av[i][j][r]);
            *(u16x4*)&Vtb[(((bb_ * H_ + h) * D_ + d) * T_) + tloc] = v;
        }
    }
}

// ---------------------------------------------------------------------------
// GEMM core, double-buffered (used by proj).
// ---------------------------------------------------------------------------
__device__ __forceinline__ void gemm_core_128_db(
    const u16* __restrict__ A, const u16* __restrict__ B,
    u16* As, u16* Bs, int m0, int n0, f32x4 (&acc)[4][4])
{
    const int K = C_;
    const int KT = K / 32;
    int tid  = threadIdx.x;
    int lane = tid & 63, w = tid >> 6;
    int quad = lane >> 4, l15 = lane & 15;
    int wm = w >> 1, wn = w & 1;

    int c0 = tid, c1 = tid + 256;
    int row0 = c0 >> 2, row1 = c1 >> 2;
    int gc0 = (((c0 & 3) - (row0 >> 1)) & 3) * 8;
    int gc1 = (((c1 & 3) - (row1 >> 1)) & 3) * 8;
    int ldsb0 = (w * 64) * 16;
    int ldsb1 = (256 + w * 64) * 16;

    const u16* ApA = A + (size_t)(m0 + row0) * K + gc0;
    const u16* ApB = A + (size_t)(m0 + row1) * K + gc1;
    const u16* BpA = B + (size_t)(n0 + row0) * K + gc0;
    const u16* BpB = B + (size_t)(n0 + row1) * K + gc1;

    char* As0 = (char*)As; char* As1 = (char*)As + 8192;
    char* Bs0 = (char*)Bs; char* Bs1 = (char*)Bs + 8192;

    int aoff[4], boff[4];
#pragma unroll
    for (int i = 0; i < 4; ++i) {
        int rA = wm * 64 + i * 16 + l15;
        aoff[i] = (rA * 32 + (((rA >> 1) + quad) & 3) * 8) * 2;
        int rB = wn * 64 + i * 16 + l15;
        boff[i] = (rB * 32 + (((rB >> 1) + quad) & 3) * 8) * 2;
    }

    async16(ApA, As0 + ldsb0); async16(ApB, As0 + ldsb1);
    async16(BpA, Bs0 + ldsb0); async16(BpB, Bs0 + ldsb1);
    ApA += 32; ApB += 32; BpA += 32; BpB += 32;

    auto body = [&](int kt, const char* Ac, const char* Bc, char* Apf, char* Bpf) {
        __syncthreads();
        if (kt + 1 < KT) {
            async16(ApA, Apf + ldsb0); async16(ApB, Apf + ldsb1);
            async16(BpA, Bpf + ldsb0); async16(BpB, Bpf + ldsb1);
        }
        ApA += 32; ApB += 32; BpA += 32; BpB += 32;

        bf16x8 a[4], b[4];
#pragma unroll
        for (int i = 0; i < 4; ++i) {
            a[i] = *(const bf16x8*)(Ac + aoff[i]);
            b[i] = *(const bf16x8*)(Bc + boff[i]);
        }
#pragma unroll
        for (int i = 0; i < 4; ++i)
#pragma unroll
            for (int j = 0; j < 4; ++j)
                acc[i][j] = __builtin_amdgcn_mfma_f32_16x16x32_bf16(a[i], b[j], acc[i][j], 0, 0, 0);
    };

    for (int kt = 0; kt < KT; kt += 2) {
        body(kt,     As0, Bs0, As1, Bs1);
        body(kt + 1, As1, Bs1, As0, Bs0);
    }
}

// ---------------------------------------------------------------------------
// Flash attention (causal), S^T/O^T, max-free softmax, register-resident P.
// R11 grid: 1024 blocks = 16 pairs x 64 bh.  Block (j, bh) processes the
// 64-row Q-tiles qt=j then qt=31-j -> exactly 33 K-tiles per block, all
// blocks uniform.  4 blocks/CU co-resident (LDS 32KB) = 16 waves/CU.
// Wave w owns the tile's t-cols w*16..w*16+15.  l via ones-MFMA.
// ---------------------------------------------------------------------------
__global__ __launch_bounds__(256, 4) void attn_kernel(
    const u16* __restrict__ Qb, const u16* __restrict__ Kb,
    const u16* __restrict__ Vtb, u16* __restrict__ Yb)
{
    __shared__ u16 SMA[16384];       // Ks0|Ks1|Vs0|Vs1 (4x8KB), reused by epilogue
    u16* Ks0 = SMA;
    u16* Ks1 = SMA + 4096;
    u16* Vs0 = SMA + 8192;
    u16* Vs1 = SMA + 12288;

    int id = blockIdx.x;
    int bh = id & 63;
    int jj = id >> 6;                // 0..15

    int tid = threadIdx.x, lane = tid & 63, w = tid >> 6;
    int quad = lane >> 4, l15 = lane & 15;
    int b = bh >> 4, h = bh & 15;

    // loop-invariant LDS byte offsets (K: 8 x b128, V: 16 x b64)
    int koff0[4], koff1[4], voff[4][4];
#pragma unroll
    for (int sblk = 0; sblk < 4; ++sblk) {
        int sr = sblk * 16 + l15;
        koff0[sblk] = (sr * 64 + ((quad + sr) & 7) * 8) * 2;
        koff1[sblk] = (sr * 64 + ((4 + quad + sr) & 7) * 8) * 2;
    }
#pragma unroll
    for (int n = 0; n < 4; ++n)
#pragma unroll
        for (int sblk = 0; sblk < 4; ++sblk) {
            int dr = n * 16 + l15;
            voff[n][sblk] = (dr * 64 + ((sblk * 2 + (quad >> 1) + dr) & 7) * 8 + (quad & 1) * 4) * 2;
        }

    // staging chunk assignment (512 chunks of 16B per 8KB tile, 2 passes)
    int cA = tid, cB = tid + 256;
    int sA = cA >> 3, sB = cB >> 3;
    int offA = (((cA & 7) - sA) & 7) * 8;
    int offB = (((cB & 7) - sB) & 7) * 8;
    const u16* Kbase = Kb + (size_t)(b * T_) * C_ + h * 64;
    const u16* Vbase = Vtb + (size_t)bh * D_ * T_;
    int ldsb0 = (w * 64) * 16, ldsb1 = (256 + w * 64) * 16;

    const s16x4 ones = { (short)0x3F80, (short)0x3F80, (short)0x3F80, (short)0x3F80 };
    const f32x4 z4 = {0.f, 0.f, 0.f, 0.f};

    int qts[2] = { jj, 31 - jj };

    for (int pass = 0; pass < 2; ++pass) {
        int qt = qts[pass];
        int qbase = qt * 64;

        if (pass) __syncthreads();   // prior epilogue LDS reads done

        // Q B-frags from [BT,C]: wave w owns t = qbase + w*16 + l15
        bf16x8 qf0, qf1;
        {
            const u16* q0 = Qb + ((size_t)(b * T_ + qbase + w * 16 + l15)) * C_ + h * 64;
            qf0 = *(const bf16x8*)(q0 + quad * 8);
            qf1 = *(const bf16x8*)(q0 + 32 + quad * 8);
        }

        f32x4 o_acc[4];              // O^T: col t (l15), rows d=n*16+quad*4+r
        f32x4 l_acc = z4;            // all 4 regs identical = sum_s P[s,t]
#pragma unroll
        for (int n = 0; n < 4; ++n) o_acc[n] = z4;

        const int nst = qt + 1;      // number of 64-row K-tiles

        const u16* kgpA = Kbase + (size_t)sA * C_ + offA;
        const u16* kgpB = Kbase + (size_t)sB * C_ + offB;
        const u16* vgpA = Vbase + sA * T_ + offA;
        const u16* vgpB = Vbase + sB * T_ + offB;

        // prologue: stage tile 0 into buffer 0
        async16(kgpA, (char*)Ks0 + ldsb0);
        async16(kgpB, (char*)Ks0 + ldsb1);
        async16(vgpA, (char*)Vs0 + ldsb0);
        async16(vgpB, (char*)Vs0 + ldsb1);
        kgpA += 64 * C_; kgpB += 64 * C_; vgpA += 64; vgpB += 64;

        auto tile_body = [&](int st, const u16* K_, const u16* V_, char* Kpf, char* Vpf) {
            __syncthreads();   // tile st resident; prev reads done
            if (st + 1 < nst) {
                async16(kgpA, Kpf + ldsb0);
                async16(kgpB, Kpf + ldsb1);
                async16(vgpA, Vpf + ldsb0);
                async16(vgpB, Vpf + ldsb1);
            }
            kgpA += 64 * C_; kgpB += 64 * C_; vgpA += 64; vgpB += 64;

            // S^T = K Q^T : per wave 64(s) x 16(t)
            f32x4 sv[4];
#pragma unroll
            for (int sblk = 0; sblk < 4; ++sblk) {
                bf16x8 k0 = *(const bf16x8*)((const char*)K_ + koff0[sblk]);
                bf16x8 k1 = *(const bf16x8*)((const char*)K_ + koff1[sblk]);
                f32x4 t0 = __builtin_amdgcn_mfma_f32_16x16x32_bf16(k0, qf0, z4, 0, 0, 0);
                sv[sblk] = __builtin_amdgcn_mfma_f32_16x16x32_bf16(k1, qf1, t0, 0, 0, 0);
            }

            if (st == qt) {   // diagonal tile: causal mask (s > t), tile-local
                int tl = w * 16 + l15;
#pragma unroll
                for (int sblk = 0; sblk < 4; ++sblk)
#pragma unroll
                    for (int r = 0; r < 4; ++r)
                        if (sblk * 16 + quad * 4 + r > tl) sv[sblk][r] = -1e30f;
            }

            // max-free softmax: raw v_exp_f32, P packed to regs; l via ones-MFMA
            s16x4 pfrag[4];
#pragma unroll
            for (int sblk = 0; sblk < 4; ++sblk) {
#pragma unroll
                for (int r = 0; r < 4; ++r)
                    sv[sblk][r] = __builtin_amdgcn_exp2f(sv[sblk][r]);
                uint2 pk;
                pk.x = pk_bf16(sv[sblk][0], sv[sblk][1]);
                pk.y = pk_bf16(sv[sblk][2], sv[sblk][3]);
                pfrag[sblk] = *(s16x4*)&pk;
                l_acc = __builtin_amdgcn_mfma_f32_16x16x16bf16_1k(ones, pfrag[sblk], l_acc, 0, 0, 0);
            }

            // O^T += V^T P via mfma 16x16x16: A = V^T (LDS b64), B = pfrag
#pragma unroll
            for (int n = 0; n < 4; ++n)
#pragma unroll
                for (int sblk = 0; sblk < 4; ++sblk) {
                    s16x4 va = *(const s16x4*)((const char*)V_ + voff[n][sblk]);
                    o_acc[n] = __builtin_amdgcn_mfma_f32_16x16x16bf16_1k(va, pfrag[sblk], o_acc[n], 0, 0, 0);
                }
        };

        for (int st = 0; st < nst; st += 2) {
            tile_body(st, Ks0, Vs0, (char*)Ks1, (char*)Vs1);
            if (st + 1 < nst)
                tile_body(st + 1, Ks1, Vs1, (char*)Ks0, (char*)Vs0);
        }

        // epilogue: LDS transpose (wave-private, stride 72) -> coalesced stores
        __syncthreads();             // all waves done reading K/V LDS
        u16* PW = SMA + w * 1152;    // 16 rows x 72 elems per wave
        {
            float inv = 1.0f / l_acc[0];   // all regs equal (ones-MFMA)
#pragma unroll
            for (int n = 0; n < 4; ++n) {
                uint2 pk;
                pk.x = pk_bf16(o_acc[n][0] * inv, o_acc[n][1] * inv);
                pk.y = pk_bf16(o_acc[n][2] * inv, o_acc[n][3] * inv);
                *(u16x4*)&PW[l15 * 72 + n * 16 + quad * 4] = *(u16x4*)&pk;
            }
        }
        asm volatile("s_waitcnt lgkmcnt(0)" ::: "memory");   // wave-private
#pragma unroll
        for (int st = 0; st < 2; ++st) {
            int tr = st * 8 + (lane >> 3);      // 0..15
            int d8 = (lane & 7) * 8;
            u16x8 v = *(u16x8*)&PW[tr * 72 + d8];
            *(u16x8*)&Yb[(size_t)(b * T_ + qbase + w * 16 + tr) * C_ + h * 64 + d8] = v;
        }
    }
}

// ---------------------------------------------------------------------------
// Output projection, XCD-pinned 1-D grid (512 blocks), C^T orientation.
// Epilogue: fp32 LDS transpose in 2 ch-halves (stride 68) -> float4 stores.
// ---------------------------------------------------------------------------
__global__ __launch_bounds__(256, 4) void proj_gemm(
    const u16* __restrict__ Yb, const u16* __restrict__ Wob,
    const float* __restrict__ bo, float* __restrict__ out)
{
    __shared__ u16 SM[17408];
    u16* As = SM;
    u16* Bs = SM + 8192;

    int id = blockIdx.x;
    int xcd = id & 7;
    int local = id >> 3;
    int by = xcd * 8 + (local & 7);
    int bx = local >> 3;
    int m0 = bx * 128, n0 = by * 128;

    f32x4 acc[4][4];
    const f32x4 z4 = {0.f, 0.f, 0.f, 0.f};
#pragma unroll
    for (int i = 0; i < 4; ++i)
#pragma unroll
        for (int j = 0; j < 4; ++j) acc[i][j] = z4;

    gemm_core_128_db(Wob, Yb, As, Bs, m0, n0, acc);

    int lane = threadIdx.x & 63, w = threadIdx.x >> 6;
    int quad = lane >> 4, l15 = lane & 15;
    int wm = w >> 1, wn = w & 1;

    float* LF = (float*)SM;
    __syncthreads();
#pragma unroll
    for (int hh = 0; hh < 2; ++hh) {
        if (wm == hh) {
#pragma unroll
            for (int i = 0; i < 4; ++i) {
                int chl = i * 16 + quad * 4;
#pragma unroll
                for (int j = 0; j < 4; ++j) {
                    int tl = wn * 64 + j * 16 + l15;
                    *(f32x4*)&LF[tl * 68 + chl] = acc[i][j];
                }
            }
        }
        __syncthreads();
        f32x4 b4 = *(const f32x4*)&bo[m0 + hh * 64 + (lane & 15) * 4];
#pragma unroll
        for (int st = 0; st < 8; ++st) {
            int tl = w * 32 + st * 4 + (lane >> 4);
            int ch4 = (lane & 15) * 4;
            f32x4 v = *(f32x4*)&LF[tl * 68 + ch4];
            v += b4;
            *(f32x4*)&out[(size_t)(n0 + tl) * C_ + m0 + hh * 64 + ch4] = v;
        }
        if (hh == 0) __syncthreads();
    }
}

// ---------------------------------------------------------------------------
// launch
// ---------------------------------------------------------------------------
extern "C" void kernel_launch(void* const* d_in, const int* in_sizes, int n_in,
                              void* d_out, int out_size, void* d_ws, size_t ws_size,
                              hipStream_t stream) {
    const float* X  = (const float*)d_in[0];
    const float* Wq = (const float*)d_in[1];
    const float* Wk = (const float*)d_in[2];
    const float* Wv = (const float*)d_in[3];
    const float* Wo = (const float*)d_in[4];
    const float* bo = (const float*)d_in[5];

    char* ws = (char*)d_ws;
    u16* Xb  = (u16*)(ws);                       // 16 MB  [BT, C] bf16
    u16* Wqb = (u16*)(ws + (16u << 20));         //  2 MB
    u16* Wkb = (u16*)(ws + (18u << 20));         //  2 MB
    u16* Wvb = (u16*)(ws + (20u << 20));         //  2 MB
    u16* Wob = (u16*)(ws + (22u << 20));         //  2 MB
    u16* Qb  = (u16*)(ws + (24u << 20));         // 16 MB  [BT, C] (pre-scaled)
    u16* Kb  = (u16*)(ws + (40u << 20));         // 16 MB  [BT, C]
    u16* Vtb = (u16*)(ws + (56u << 20));         // 16 MB  [B,H,D,T]
    u16* Yb  = (u16*)(ws + (72u << 20));         // 16 MB  [BT, C]

    cast_all_kernel<<<dim3(8192 + 4 * 1024), 256, 0, stream>>>(
        X, Wq, Wk, Wv, Wo, Xb, Wqb, Wkb, Wvb, Wob);

    qkv_gemm<<<dim3(512), 256, 0, stream>>>(Xb, Wqb, Wkb, Wvb, Qb, Kb, Vtb);
    attn_kernel<<<dim3(1024), 256, 0, stream>>>(Qb, Kb, Vtb, Yb);
    proj_gemm<<<dim3(8 * 64), 256, 0, stream>>>(Yb, Wob, bo, (float*)d_out);
}